// Round 15
// baseline (277.859 us; speedup 1.0000x reference)
//
#include <hip/hip_runtime.h>
#include <hip/hip_bf16.h>
#include <math.h>

#define B 4
#define T 1024
#define KDIM 64
#define R 32
#define NH 8
#define NEGBIG (-1e30f)

typedef __hip_bfloat16 bf16;
typedef __attribute__((ext_vector_type(8))) short bf16x8s;
typedef __attribute__((ext_vector_type(4))) short bf16x4s;
typedef __attribute__((ext_vector_type(4))) float f32x4;

static __device__ __forceinline__ float b2f(bf16 x) { return __bfloat162float(x); }
static __device__ __forceinline__ bf16 f2b(float x) { return __float2bfloat16(x); }
static __device__ __forceinline__ float sigmoidf_(float x) { return 1.0f / (1.0f + __expf(-x)); }
static __device__ __forceinline__ float siluf_(float x) { return x * sigmoidf_(x); }

static __device__ __forceinline__ float waveSum64(float v) {
    #pragma unroll
    for (int m = 32; m >= 1; m >>= 1) v += __shfl_xor(v, m);
    return v;
}

// ---------------- Kernel 1a: x3 = bn(squeeze conv)  +  fused weight prep ----------------
__global__ __launch_bounds__(256) void k1a_x3(const float* __restrict__ x, const float* __restrict__ sqw,
                                              const float* __restrict__ bng, const float* __restrict__ bnb,
                                              const float* __restrict__ wq, const float* __restrict__ wk,
                                              const float* __restrict__ wv, const float* __restrict__ wl,
                                              const float* __restrict__ uniw, const float* __restrict__ ffw1,
                                              const float* __restrict__ ffw2,
                                              float* __restrict__ x3,
                                              bf16* __restrict__ BqT, bf16* __restrict__ BkT,
                                              bf16* __restrict__ BvT, bf16* __restrict__ BlT,
                                              bf16* __restrict__ uniwT, bf16* __restrict__ ffw1T,
                                              bf16* __restrict__ ffw2T) {
    int blk = blockIdx.x;               // 512 blocks
    int b = blk >> 7, t0 = (blk & 127) << 3;
    int row = threadIdx.x >> 5, o = threadIdx.x & 31;
    int tt = t0 + row;
    const float* xr = x + (size_t)(b * T + tt) * KDIM;
    const float* wr = sqw + o * KDIM;
    float acc = 0.f;
    #pragma unroll
    for (int i = 0; i < KDIM; ++i) acc += xr[i] * wr[i];
    const float inv = 0.9999950000374997f; // 1/sqrt(1+1e-5)
    x3[(size_t)(b * T + tt) * R + o] = bng[o] * acc * inv + bnb[o];

    int gid = blk * 256 + threadIdx.x;
    // conv weights, s-major K (read-coalesced)
    #pragma unroll
    for (int rep = 0; rep < 3; ++rep) {
        int e = gid + rep * 131072;
        if (e < 163840) {
            int oo = e / 320, rem = e - oo * 320;
            int i = rem / 5, s = rem - i * 5;
            BqT[oo * 320 + s * 64 + i] = f2b(wq[e]);
        } else if (e < 327680) {
            int e2 = e - 163840;
            int oo = e2 / 320, rem = e2 - oo * 320;
            int i = rem / 5, s = rem - i * 5;
            BkT[oo * 320 + s * 64 + i] = f2b(wk[e2]);
        } else if (e < 360448) {
            int e3 = e - 327680;
            BvT[e3] = f2b(wv[e3]);
        } else {
            int e4 = e - 360448;
            BlT[e4] = f2b(wl[e4]);
        }
    }
    // epilogue weights (read-coalesced): uniwT[c][d], ffw1T[j][i], ffw2T[c][j]
    {
        int e = gid;
        if (e < 65536) {
            int d = e >> 6, c = e & 63;
            uniwT[c * 1024 + d] = f2b(uniw[e]);
        } else if (e < 81920) {
            int e2 = e - 65536;
            int i = e2 >> 8, j = e2 & 255;
            ffw1T[j * 64 + i] = f2b(ffw1[e2]);
        } else if (e < 98304) {
            int e3 = e - 81920;
            int j = e3 >> 6, c = e3 & 63;
            ffw2T[c * 256 + j] = f2b(ffw2[e3]);
        }
    }
}

// ---------------- Kernel 1b: depthwise diff + excite conv + gate + pos ----------------
__global__ __launch_bounds__(256) void k1b_xin(const float* __restrict__ x3, const float* __restrict__ dww,
                                               const float* __restrict__ exw, const float* __restrict__ x,
                                               const float* __restrict__ pos, float* __restrict__ xin) {
    __shared__ float sx3[10 * R];
    __shared__ float sxp[8 * R];
    int blk = blockIdx.x;               // 512 blocks
    int b = blk >> 7, t0 = (blk & 127) << 3;
    int tid = threadIdx.x;
    for (int e = tid; e < 320; e += 256) {
        int rr = e >> 5, o = e & 31;
        int tt = t0 + rr;
        sx3[e] = (tt < T) ? x3[(size_t)(b * T + tt) * R + o] : 0.f;
    }
    __syncthreads();
    {
        int rr = tid >> 5, o = tid & 31;
        int tt = t0 + rr;
        float v;
        if (tt == T - 1) {
            v = sx3[rr * R + o];
        } else {
            float w0 = dww[o * 3 + 0], w1 = dww[o * 3 + 1], w2 = dww[o * 3 + 2];
            v = sx3[rr * R + o] * (w0 - 1.f) + sx3[(rr + 1) * R + o] * w1 + sx3[(rr + 2) * R + o] * w2;
        }
        sxp[rr * R + o] = v;
    }
    __syncthreads();
    int rr = tid >> 5, c0 = tid & 31;
    int tt = t0 + rr;
    #pragma unroll
    for (int u = 0; u < 2; ++u) {
        int c = c0 + u * 32;
        const float* ew = exw + c * R;
        float g = 0.f;
        #pragma unroll
        for (int o = 0; o < R; ++o) g += ew[o] * sxp[rr * R + o];
        float sg = sigmoidf_(g);
        size_t idx = (size_t)(b * T + tt) * KDIM + c;
        xin[idx] = x[idx] * sg + pos[tt * KDIM + c];
    }
}

// ---------------- Kernel 2 (MFMA): q/k/v/l convs + silu + head-scramble store ----------------
__global__ __launch_bounds__(256) void k2_mfma(const float* __restrict__ xin,
        const bf16* __restrict__ BqT, const bf16* __restrict__ BkT,
        const bf16* __restrict__ BvT, const bf16* __restrict__ BlT,
        const float* __restrict__ bq, const float* __restrict__ bk,
        bf16* __restrict__ qo, bf16* __restrict__ ko, bf16* __restrict__ vt, bf16* __restrict__ lo) {
    __shared__ __align__(16) bf16 sX[24][72];
    int blk = blockIdx.x;               // 512 blocks
    int sel = blk >> 8;                 // 0: q+v, 1: k+l
    int b = (blk >> 6) & 3, t0 = (blk & 63) << 4;
    int tid = threadIdx.x, w = tid >> 6, lane = tid & 63;
    int lm = lane & 15, quad = lane >> 4;

    for (int e = tid; e < 1536; e += 256) {
        int rr = e >> 6, ch = e & 63;
        int t = t0 - 8 + rr;
        sX[rr][ch] = f2b((t >= 0) ? xin[((size_t)(b * T) + t) * KDIM + ch] : 0.f);
    }
    __syncthreads();

    bf16x8s aX[10];
    #pragma unroll
    for (int ks = 0; ks < 10; ++ks)
        aX[ks] = *(const bf16x8s*)&sX[lm + 2 * (ks >> 1)][(ks & 1) * 32 + quad * 8];

    const bf16* Bd = sel ? BkT : BqT;
    const float* bias = sel ? bk : bq;
    const bf16* Bp = sel ? BlT : BvT;
    bf16* OutD = sel ? ko : qo;
    const float isg = 0.35355339059327373f; // 1/64^0.25

    for (int nt8 = 0; nt8 < 8; ++nt8) {
        int nt = w * 8 + nt8;
        int o = nt * 16 + lm;
        f32x4 acc = {0.f, 0.f, 0.f, 0.f};
        const bf16* br = Bd + (size_t)o * 320;
        #pragma unroll
        for (int ks = 0; ks < 10; ++ks) {
            bf16x8s bB = *(const bf16x8s*)&br[ks * 32 + quad * 8];
            acc = __builtin_amdgcn_mfma_f32_16x16x32_bf16(aX[ks], bB, acc, 0, 0, 0);
        }
        float bb = bias[o];
        int c = o >> 3, h = o & 7;
        #pragma unroll
        for (int r4 = 0; r4 < 4; ++r4) {
            int tt = t0 + quad * 4 + r4;
            int n = (b << 3) + (tt >> 7);
            int pp = ((tt & 127) << 3) | h;
            OutD[((size_t)n * T + pp) * KDIM + c] = f2b(siluf_(acc[r4] + bb) * isg);
        }
    }
    for (int nt8 = 0; nt8 < 8; ++nt8) {
        int nt = w * 8 + nt8;
        int o = nt * 16 + lm;
        f32x4 acc = {0.f, 0.f, 0.f, 0.f};
        const bf16* br = Bp + (size_t)o * 64;
        #pragma unroll
        for (int ks = 0; ks < 2; ++ks) {
            bf16x8s bB = *(const bf16x8s*)&br[ks * 32 + quad * 8];
            acc = __builtin_amdgcn_mfma_f32_16x16x32_bf16(aX[8 + ks], bB, acc, 0, 0, 0);
        }
        int c = o >> 3, h = o & 7;
        #pragma unroll
        for (int r4 = 0; r4 < 4; ++r4) {
            int tt = t0 + quad * 4 + r4;
            int n = (b << 3) + (tt >> 7);
            int pp = ((tt & 127) << 3) | h;
            float val = siluf_(acc[r4]);
            if (sel == 0)
                vt[((size_t)n * 64 + c) * T + pp] = f2b(val);
            else
                lo[((size_t)n * T + pp) * KDIM + c] = f2b(val);
        }
    }
}

// ---------------- Kernel 3: local windowed causal attention (window 5) ----------------
__global__ __launch_bounds__(256) void k3_local(const bf16* __restrict__ lws, bf16* __restrict__ ol) {
    int wave = threadIdx.x >> 6, lane = threadIdx.x & 63;
    int ridx = blockIdx.x * 4 + wave;   // 8192 blocks -> 32768 rows
    int n = ridx >> 10, p = ridx & 1023;
    const bf16* base = lws + (size_t)n * T * KDIM;
    float lp = b2f(base[(size_t)p * KDIM + lane]);
    float lj[6], s[6];
    #pragma unroll
    for (int u = 0; u < 6; ++u) {
        int j = p - 5 + u;
        bool valid = (j >= 0);
        lj[u] = valid ? b2f(base[(size_t)j * KDIM + lane]) : 0.f;
        float d = lp * lj[u];
        d = waveSum64(d);
        s[u] = valid ? d * 0.125f : NEGBIG;
    }
    float mx = s[5];
    #pragma unroll
    for (int u = 0; u < 5; ++u) mx = fmaxf(mx, s[u]);
    float Z = 0.f, acc = 0.f;
    #pragma unroll
    for (int u = 0; u < 6; ++u) {
        float e = (s[u] <= NEGBIG) ? 0.f : __expf(s[u] - mx);
        Z += e;
        acc += e * lj[u];
    }
    ol[(size_t)(n * T + p) * KDIM + lane] = f2b(acc / Z);
}

// ---------------- Kernel 4 (MFMA, 32-row tiles, 128 threads): causal flash attention ----------------
// Block = (n, 32-row q-tile); 2 waves x 16 q-rows; grid 1024 -> 4 barrier domains/CU.
// Q read straight from global into fragments (wave touches only its own 16 rows; og alias safe).
// 4-way balance swizzle: co-resident blocks {i, i+256, i+512, i+768} have qt summing to 62.
__global__ __launch_bounds__(128) void k4_mfma(const bf16* __restrict__ qws, const bf16* __restrict__ kws,
                                               const bf16* __restrict__ vt, bf16* __restrict__ og) {
    __shared__ __align__(16) bf16 sK[64][72];
    __shared__ __align__(16) bf16 sVt[64][72];
    __shared__ __align__(16) bf16 sPt[2][16][76];

    int i = blockIdx.x;                  // 1024 blocks
    int quarter = i >> 8, rem = i & 255;
    int n = rem >> 3, sub = rem & 7;
    int qt = (quarter == 0) ? sub : (quarter == 1) ? (15 - sub)
           : (quarter == 2) ? (16 + sub) : (31 - sub);   // 0..31
    int p0 = qt << 5;
    int tid = threadIdx.x, w = tid >> 6, lane = tid & 63;
    int lm = lane & 15, quad = lane >> 4;

    // Q fragments direct from global (A-layout: row m=lm, k=quad*8+j)
    const bf16* qrow = qws + ((size_t)n * T + p0 + w * 16 + lm) * KDIM;
    bf16x8s aQ[2];
    aQ[0] = *(const bf16x8s*)&qrow[quad * 8];
    aQ[1] = *(const bf16x8s*)&qrow[32 + quad * 8];

    f32x4 O[4];
    float m_i[4], l_i[4];
    #pragma unroll
    for (int t = 0; t < 4; ++t) { O[t][0] = 0.f; O[t][1] = 0.f; O[t][2] = 0.f; O[t][3] = 0.f; }
    #pragma unroll
    for (int r4 = 0; r4 < 4; ++r4) { m_i[r4] = NEGBIG; l_i[r4] = 0.f; }

    int jtmax = (p0 + 31) >> 6;
    int prow_base = p0 + w * 16 + quad * 4;
    for (int jt = 0; jt <= jtmax; ++jt) {
        int j0 = jt << 6;
        bool diag = (jt == jtmax);
        int ntmax = diag ? ((qt & 1) * 2 + 1) : 3;
        int ksmax = diag ? (qt & 1) : 1;
        __syncthreads();   // protect prev iteration's sK/sVt readers
        {
            const uint4* kg = (const uint4*)(kws + ((size_t)n * T + j0) * KDIM);
            #pragma unroll
            for (int r = 0; r < 4; ++r) {
                int e = tid + 128 * r;           // 0..511 vec8 slots
                *(uint4*)&sK[e >> 3][(e & 7) * 8] = kg[e];
            }
            #pragma unroll
            for (int r = 0; r < 4; ++r) {
                int e = tid + 128 * r;
                int c = e >> 3, j8 = e & 7;
                *(uint4*)&sVt[c][j8 * 8] =
                    *(const uint4*)(vt + ((size_t)n * 64 + c) * T + j0 + j8 * 8);
            }
        }
        __syncthreads();

        // ---- QK^T ----
        f32x4 S[4];
        for (int nt = 0; nt <= ntmax; ++nt) {
            f32x4 acc = {0.f, 0.f, 0.f, 0.f};
            #pragma unroll
            for (int ks = 0; ks < 2; ++ks) {
                bf16x8s bK = *(const bf16x8s*)&sK[nt * 16 + lm][ks * 32 + quad * 8];
                acc = __builtin_amdgcn_mfma_f32_16x16x32_bf16(aQ[ks], bK, acc, 0, 0, 0);
            }
            S[nt] = acc;
        }
        // ---- mask + online softmax ----
        float mt[4];
        #pragma unroll
        for (int r4 = 0; r4 < 4; ++r4) mt[r4] = NEGBIG;
        for (int nt = 0; nt <= ntmax; ++nt) {
            int jcol = j0 + nt * 16 + lm;
            #pragma unroll
            for (int r4 = 0; r4 < 4; ++r4) {
                float s = (jcol <= prow_base + r4) ? S[nt][r4] : NEGBIG;
                S[nt][r4] = s;
                mt[r4] = fmaxf(mt[r4], s);
            }
        }
        #pragma unroll
        for (int r4 = 0; r4 < 4; ++r4) {
            float v = mt[r4];
            v = fmaxf(v, __shfl_xor(v, 1)); v = fmaxf(v, __shfl_xor(v, 2));
            v = fmaxf(v, __shfl_xor(v, 4)); v = fmaxf(v, __shfl_xor(v, 8));
            mt[r4] = v;
        }
        float alpha[4], ps[4];
        #pragma unroll
        for (int r4 = 0; r4 < 4; ++r4) {
            float mnew = fmaxf(m_i[r4], mt[r4]);
            alpha[r4] = __expf(m_i[r4] - mnew);
            m_i[r4] = mnew; ps[r4] = 0.f;
        }
        for (int nt = 0; nt <= ntmax; ++nt) {
            #pragma unroll
            for (int r4 = 0; r4 < 4; ++r4) {
                float p = (S[nt][r4] <= NEGBIG) ? 0.f : __expf(S[nt][r4] - m_i[r4]);
                ps[r4] += p;
                sPt[w][quad * 4 + r4][nt * 16 + lm] = f2b(p);
            }
        }
        #pragma unroll
        for (int r4 = 0; r4 < 4; ++r4) {
            float v = ps[r4];
            v += __shfl_xor(v, 1); v += __shfl_xor(v, 2);
            v += __shfl_xor(v, 4); v += __shfl_xor(v, 8);
            l_i[r4] = l_i[r4] * alpha[r4] + v;
        }
        #pragma unroll
        for (int t = 0; t < 4; ++t)
            #pragma unroll
            for (int r4 = 0; r4 < 4; ++r4) O[t][r4] *= alpha[r4];
        // wave-private LDS handoff: pin write->read ordering
        __builtin_amdgcn_wave_barrier();
        // ---- PV (reads only columns written this iteration: ks<=ksmax covers nt<=ntmax) ----
        for (int ks = 0; ks <= ksmax; ++ks) {
            bf16x4s plo = *(const bf16x4s*)&sPt[w][lm][ks * 32 + quad * 8];
            bf16x4s phi = *(const bf16x4s*)&sPt[w][lm][ks * 32 + quad * 8 + 4];
            bf16x8s aP;
            #pragma unroll
            for (int ii = 0; ii < 4; ++ii) { aP[ii] = plo[ii]; aP[ii + 4] = phi[ii]; }
            #pragma unroll
            for (int ct = 0; ct < 4; ++ct) {
                bf16x8s bV = *(const bf16x8s*)&sVt[ct * 16 + lm][ks * 32 + quad * 8];
                O[ct] = __builtin_amdgcn_mfma_f32_16x16x32_bf16(aP, bV, O[ct], 0, 0, 0);
            }
        }
    }
    #pragma unroll
    for (int r4 = 0; r4 < 4; ++r4) {
        int p = p0 + w * 16 + quad * 4 + r4;
        float inv = 1.f / l_i[r4];
        bf16* ob = og + ((size_t)n * T + p) * KDIM;
        #pragma unroll
        for (int t = 0; t < 4; ++t) ob[t * 16 + lm] = f2b(O[t][r4] * inv);
    }
}

// ---------------- Kernel 5 (MFMA): gate/concat + uni GEMM + LN1 + FF + LN2 ----------------
__global__ __launch_bounds__(256) void k5_mfma(const bf16* __restrict__ og, const bf16* __restrict__ olw,
        const bf16* __restrict__ uniwT, const float* __restrict__ unib, const float* __restrict__ xin,
        const float* __restrict__ ln1g, const float* __restrict__ ln1b,
        const bf16* __restrict__ ffw1T, const float* __restrict__ ffb1,
        const bf16* __restrict__ ffw2T, const float* __restrict__ ffb2,
        const float* __restrict__ ln2g, const float* __restrict__ ln2b,
        float* __restrict__ out) {
    __shared__ __align__(16) bf16 sU[16][1032];
    __shared__ float sY[16][68];
    __shared__ __align__(16) bf16 sYb[16][72];
    __shared__ __align__(16) bf16 sH[16][264];
    int blk = blockIdx.x;               // 256 blocks
    int b = blk >> 6, t0 = (blk & 63) << 4;
    int tid = threadIdx.x, w = tid >> 6, lane = tid & 63;
    int lm = lane & 15, quad = lane >> 4;

    for (int e = tid; e < 16384; e += 256) {
        int r = e >> 10, d = e & 1023;
        int hh = d >> 6, c = d & 63, hi = hh & 7;
        size_t idx = ((size_t)((b * NH + hi) * T) + t0 + r) * KDIM + c;
        float gv = b2f(og[idx]);
        float sg = sigmoidf_(gv);
        sU[r][d] = f2b((hh < 8) ? (1.f - sg) * b2f(olw[idx]) : sg * gv);
    }
    __syncthreads();

    int col = w * 16 + lm;
    f32x4 accU = {0.f, 0.f, 0.f, 0.f};
    const bf16* ur = uniwT + (size_t)col * 1024;
    #pragma unroll
    for (int ks = 0; ks < 32; ++ks) {
        bf16x8s aU = *(const bf16x8s*)&sU[lm][ks * 32 + quad * 8];
        bf16x8s bU = *(const bf16x8s*)&ur[ks * 32 + quad * 8];
        accU = __builtin_amdgcn_mfma_f32_16x16x32_bf16(aU, bU, accU, 0, 0, 0);
    }
    float ub = unib[col];
    #pragma unroll
    for (int r4 = 0; r4 < 4; ++r4) {
        int row = quad * 4 + r4;
        float a = siluf_(accU[r4] + ub);
        sY[row][col] = a + xin[((size_t)(b * T) + t0 + row) * KDIM + col];
    }
    __syncthreads();

    #pragma unroll
    for (int i = 0; i < 4; ++i) {
        int row = w + 4 * i;
        float yv = sY[row][lane];
        float mean = waveSum64(yv) * (1.f / 64.f);
        float dv = yv - mean;
        float var = waveSum64(dv * dv) * (1.f / 64.f);
        float y = dv * rsqrtf(var + 1e-5f) * ln1g[lane] + ln1b[lane];
        sY[row][lane] = y;
        sYb[row][lane] = f2b(y);
    }
    __syncthreads();

    bf16x8s aY[2];
    #pragma unroll
    for (int ks = 0; ks < 2; ++ks) aY[ks] = *(const bf16x8s*)&sYb[lm][ks * 32 + quad * 8];
    #pragma unroll
    for (int u = 0; u < 4; ++u) {
        int j = (w * 4 + u) * 16 + lm;
        f32x4 acc = {0.f, 0.f, 0.f, 0.f};
        const bf16* fr = ffw1T + (size_t)j * 64;
        #pragma unroll
        for (int ks = 0; ks < 2; ++ks) {
            bf16x8s bF = *(const bf16x8s*)&fr[ks * 32 + quad * 8];
            acc = __builtin_amdgcn_mfma_f32_16x16x32_bf16(aY[ks], bF, acc, 0, 0, 0);
        }
        float b1 = ffb1[j];
        #pragma unroll
        for (int r4 = 0; r4 < 4; ++r4)
            sH[quad * 4 + r4][j] = f2b(fmaxf(acc[r4] + b1, 0.f));
    }
    __syncthreads();

    f32x4 accF = {0.f, 0.f, 0.f, 0.f};
    const bf16* f2r = ffw2T + (size_t)col * 256;
    #pragma unroll
    for (int ks = 0; ks < 8; ++ks) {
        bf16x8s aH = *(const bf16x8s*)&sH[lm][ks * 32 + quad * 8];
        bf16x8s bF2 = *(const bf16x8s*)&f2r[ks * 32 + quad * 8];
        accF = __builtin_amdgcn_mfma_f32_16x16x32_bf16(aH, bF2, accF, 0, 0, 0);
    }
    float b2 = ffb2[col];
    #pragma unroll
    for (int r4 = 0; r4 < 4; ++r4) {
        int row = quad * 4 + r4;
        sY[row][col] = (accF[r4] + b2) + sY[row][col];
    }
    __syncthreads();

    #pragma unroll
    for (int i = 0; i < 4; ++i) {
        int row = w + 4 * i;
        float z = sY[row][lane];
        float mean = waveSum64(z) * (1.f / 64.f);
        float dv = z - mean;
        float var = waveSum64(dv * dv) * (1.f / 64.f);
        out[((size_t)(b * T) + t0 + row) * KDIM + lane] =
            dv * rsqrtf(var + 1e-5f) * ln2g[lane] + ln2b[lane];
    }
}

extern "C" void kernel_launch(void* const* d_in, const int* in_sizes, int n_in,
                              void* d_out, int out_size, void* d_ws, size_t ws_size,
                              hipStream_t stream) {
    (void)in_sizes; (void)n_in; (void)out_size; (void)ws_size;
    const float* x    = (const float*)d_in[0];
    const float* sqw  = (const float*)d_in[1];
    const float* bng  = (const float*)d_in[2];
    const float* bnb  = (const float*)d_in[3];
    const float* dww  = (const float*)d_in[4];
    const float* exw  = (const float*)d_in[5];
    const float* pos  = (const float*)d_in[6];
    const float* wq   = (const float*)d_in[7];
    const float* bq   = (const float*)d_in[8];
    const float* wk   = (const float*)d_in[9];
    const float* bk   = (const float*)d_in[10];
    const float* wv   = (const float*)d_in[11];
    const float* wl   = (const float*)d_in[12];
    const float* uniw = (const float*)d_in[13];
    const float* unib = (const float*)d_in[14];
    const float* ln1g = (const float*)d_in[15];
    const float* ln1b = (const float*)d_in[16];
    const float* ln2g = (const float*)d_in[17];
    const float* ln2b = (const float*)d_in[18];
    const float* ffw1 = (const float*)d_in[19];
    const float* ffb1 = (const float*)d_in[20];
    const float* ffw2 = (const float*)d_in[21];
    const float* ffb2 = (const float*)d_in[22];

    // ws layout — ~22.5 MiB.
    char* ws = (char*)d_ws;
    float* xin   = (float*)(ws);                  // fp32 1.0 MiB
    bf16*  qog   = (bf16*)(ws + 0x100000);        // 4 MiB  q, then og in-place
    bf16*  kw_   = (bf16*)(ws + 0x500000);        // 4 MiB
    bf16*  vtw   = (bf16*)(ws + 0x900000);        // 4 MiB  (transposed v)
    bf16*  lw_   = (bf16*)(ws + 0xD00000);        // 4 MiB
    bf16*  olw   = (bf16*)(ws + 0x1100000);       // 4 MiB
    float* x3    = (float*)(ws + 0x1500000);      // fp32 0.5 MiB
    bf16*  BqT   = (bf16*)(ws + 0x1580000);       // 320 KiB
    bf16*  BkT   = (bf16*)(ws + 0x15D0000);       // 320 KiB
    bf16*  BvT   = (bf16*)(ws + 0x1620000);       // 64 KiB
    bf16*  BlT   = (bf16*)(ws + 0x1630000);       // 64 KiB
    bf16*  uniwT = (bf16*)(ws + 0x1640000);       // 128 KiB
    bf16*  ffw1T = (bf16*)(ws + 0x1660000);       // 32 KiB
    bf16*  ffw2T = (bf16*)(ws + 0x1668000);       // 32 KiB (end 0x1670000)

    k1a_x3 <<<512, 256, 0, stream>>>(x, sqw, bng, bnb, wq, wk, wv, wl, uniw, ffw1, ffw2,
                                     x3, BqT, BkT, BvT, BlT, uniwT, ffw1T, ffw2T);
    k1b_xin<<<512, 256, 0, stream>>>(x3, dww, exw, x, pos, xin);
    k2_mfma<<<512, 256, 0, stream>>>(xin, BqT, BkT, BvT, BlT, bq, bk, qog, kw_, vtw, lw_);
    k3_local<<<8192, 256, 0, stream>>>(lw_, olw);
    k4_mfma<<<1024, 128, 0, stream>>>(qog, kw_, vtw, qog);   // og overwrites q in-place
    k5_mfma<<<256, 256, 0, stream>>>(qog, olw, uniwT, unib, xin,
                                     ln1g, ln1b, ffw1T, ffb1, ffw2T, ffb2, ln2g, ln2b,
                                     (float*)d_out);
}

// Round 16
// 233.116 us; speedup vs baseline: 1.1919x; 1.1919x over previous
//
#include <hip/hip_runtime.h>
#include <hip/hip_bf16.h>
#include <math.h>

#define B 4
#define T 1024
#define KDIM 64
#define R 32
#define NH 8
#define NEGBIG (-1e30f)

typedef __hip_bfloat16 bf16;
typedef __attribute__((ext_vector_type(8))) short bf16x8s;
typedef __attribute__((ext_vector_type(4))) short bf16x4s;
typedef __attribute__((ext_vector_type(4))) float f32x4;

static __device__ __forceinline__ float b2f(bf16 x) { return __bfloat162float(x); }
static __device__ __forceinline__ bf16 f2b(float x) { return __float2bfloat16(x); }
static __device__ __forceinline__ float sigmoidf_(float x) { return 1.0f / (1.0f + __expf(-x)); }
static __device__ __forceinline__ float siluf_(float x) { return x * sigmoidf_(x); }

static __device__ __forceinline__ float waveSum64(float v) {
    #pragma unroll
    for (int m = 32; m >= 1; m >>= 1) v += __shfl_xor(v, m);
    return v;
}

// ---------------- Kernel 1a: x3 = bn(squeeze conv)  +  fused weight prep ----------------
__global__ __launch_bounds__(256) void k1a_x3(const float* __restrict__ x, const float* __restrict__ sqw,
                                              const float* __restrict__ bng, const float* __restrict__ bnb,
                                              const float* __restrict__ wq, const float* __restrict__ wk,
                                              const float* __restrict__ wv, const float* __restrict__ wl,
                                              const float* __restrict__ uniw, const float* __restrict__ ffw1,
                                              const float* __restrict__ ffw2,
                                              float* __restrict__ x3,
                                              bf16* __restrict__ BqT, bf16* __restrict__ BkT,
                                              bf16* __restrict__ BvT, bf16* __restrict__ BlT,
                                              bf16* __restrict__ uniwT, bf16* __restrict__ ffw1T,
                                              bf16* __restrict__ ffw2T) {
    int blk = blockIdx.x;               // 512 blocks
    int b = blk >> 7, t0 = (blk & 127) << 3;
    int row = threadIdx.x >> 5, o = threadIdx.x & 31;
    int tt = t0 + row;
    const float* xr = x + (size_t)(b * T + tt) * KDIM;
    const float* wr = sqw + o * KDIM;
    float acc = 0.f;
    #pragma unroll
    for (int i = 0; i < KDIM; ++i) acc += xr[i] * wr[i];
    const float inv = 0.9999950000374997f; // 1/sqrt(1+1e-5)
    x3[(size_t)(b * T + tt) * R + o] = bng[o] * acc * inv + bnb[o];

    int gid = blk * 256 + threadIdx.x;
    // conv weights, s-major K (read-coalesced)
    #pragma unroll
    for (int rep = 0; rep < 3; ++rep) {
        int e = gid + rep * 131072;
        if (e < 163840) {
            int oo = e / 320, rem = e - oo * 320;
            int i = rem / 5, s = rem - i * 5;
            BqT[oo * 320 + s * 64 + i] = f2b(wq[e]);
        } else if (e < 327680) {
            int e2 = e - 163840;
            int oo = e2 / 320, rem = e2 - oo * 320;
            int i = rem / 5, s = rem - i * 5;
            BkT[oo * 320 + s * 64 + i] = f2b(wk[e2]);
        } else if (e < 360448) {
            int e3 = e - 327680;
            BvT[e3] = f2b(wv[e3]);
        } else {
            int e4 = e - 360448;
            BlT[e4] = f2b(wl[e4]);
        }
    }
    // epilogue weights (read-coalesced): uniwT[c][d], ffw1T[j][i], ffw2T[c][j]
    {
        int e = gid;
        if (e < 65536) {
            int d = e >> 6, c = e & 63;
            uniwT[c * 1024 + d] = f2b(uniw[e]);
        } else if (e < 81920) {
            int e2 = e - 65536;
            int i = e2 >> 8, j = e2 & 255;
            ffw1T[j * 64 + i] = f2b(ffw1[e2]);
        } else if (e < 98304) {
            int e3 = e - 81920;
            int j = e3 >> 6, c = e3 & 63;
            ffw2T[c * 256 + j] = f2b(ffw2[e3]);
        }
    }
}

// ---------------- Kernel 1b: depthwise diff + excite conv + gate + pos ----------------
__global__ __launch_bounds__(256) void k1b_xin(const float* __restrict__ x3, const float* __restrict__ dww,
                                               const float* __restrict__ exw, const float* __restrict__ x,
                                               const float* __restrict__ pos, float* __restrict__ xin) {
    __shared__ float sx3[10 * R];
    __shared__ float sxp[8 * R];
    int blk = blockIdx.x;               // 512 blocks
    int b = blk >> 7, t0 = (blk & 127) << 3;
    int tid = threadIdx.x;
    for (int e = tid; e < 320; e += 256) {
        int rr = e >> 5, o = e & 31;
        int tt = t0 + rr;
        sx3[e] = (tt < T) ? x3[(size_t)(b * T + tt) * R + o] : 0.f;
    }
    __syncthreads();
    {
        int rr = tid >> 5, o = tid & 31;
        int tt = t0 + rr;
        float v;
        if (tt == T - 1) {
            v = sx3[rr * R + o];
        } else {
            float w0 = dww[o * 3 + 0], w1 = dww[o * 3 + 1], w2 = dww[o * 3 + 2];
            v = sx3[rr * R + o] * (w0 - 1.f) + sx3[(rr + 1) * R + o] * w1 + sx3[(rr + 2) * R + o] * w2;
        }
        sxp[rr * R + o] = v;
    }
    __syncthreads();
    int rr = tid >> 5, c0 = tid & 31;
    int tt = t0 + rr;
    #pragma unroll
    for (int u = 0; u < 2; ++u) {
        int c = c0 + u * 32;
        const float* ew = exw + c * R;
        float g = 0.f;
        #pragma unroll
        for (int o = 0; o < R; ++o) g += ew[o] * sxp[rr * R + o];
        float sg = sigmoidf_(g);
        size_t idx = (size_t)(b * T + tt) * KDIM + c;
        xin[idx] = x[idx] * sg + pos[tt * KDIM + c];
    }
}

// ---------------- Kernel 2 (MFMA): q/k/v/l convs + silu + head-scramble store ----------------
__global__ __launch_bounds__(256) void k2_mfma(const float* __restrict__ xin,
        const bf16* __restrict__ BqT, const bf16* __restrict__ BkT,
        const bf16* __restrict__ BvT, const bf16* __restrict__ BlT,
        const float* __restrict__ bq, const float* __restrict__ bk,
        bf16* __restrict__ qo, bf16* __restrict__ ko, bf16* __restrict__ vt, bf16* __restrict__ lo) {
    __shared__ __align__(16) bf16 sX[24][72];
    int blk = blockIdx.x;               // 512 blocks
    int sel = blk >> 8;                 // 0: q+v, 1: k+l
    int b = (blk >> 6) & 3, t0 = (blk & 63) << 4;
    int tid = threadIdx.x, w = tid >> 6, lane = tid & 63;
    int lm = lane & 15, quad = lane >> 4;

    for (int e = tid; e < 1536; e += 256) {
        int rr = e >> 6, ch = e & 63;
        int t = t0 - 8 + rr;
        sX[rr][ch] = f2b((t >= 0) ? xin[((size_t)(b * T) + t) * KDIM + ch] : 0.f);
    }
    __syncthreads();

    bf16x8s aX[10];
    #pragma unroll
    for (int ks = 0; ks < 10; ++ks)
        aX[ks] = *(const bf16x8s*)&sX[lm + 2 * (ks >> 1)][(ks & 1) * 32 + quad * 8];

    const bf16* Bd = sel ? BkT : BqT;
    const float* bias = sel ? bk : bq;
    const bf16* Bp = sel ? BlT : BvT;
    bf16* OutD = sel ? ko : qo;
    const float isg = 0.35355339059327373f; // 1/64^0.25

    for (int nt8 = 0; nt8 < 8; ++nt8) {
        int nt = w * 8 + nt8;
        int o = nt * 16 + lm;
        f32x4 acc = {0.f, 0.f, 0.f, 0.f};
        const bf16* br = Bd + (size_t)o * 320;
        #pragma unroll
        for (int ks = 0; ks < 10; ++ks) {
            bf16x8s bB = *(const bf16x8s*)&br[ks * 32 + quad * 8];
            acc = __builtin_amdgcn_mfma_f32_16x16x32_bf16(aX[ks], bB, acc, 0, 0, 0);
        }
        float bb = bias[o];
        int c = o >> 3, h = o & 7;
        #pragma unroll
        for (int r4 = 0; r4 < 4; ++r4) {
            int tt = t0 + quad * 4 + r4;
            int n = (b << 3) + (tt >> 7);
            int pp = ((tt & 127) << 3) | h;
            OutD[((size_t)n * T + pp) * KDIM + c] = f2b(siluf_(acc[r4] + bb) * isg);
        }
    }
    for (int nt8 = 0; nt8 < 8; ++nt8) {
        int nt = w * 8 + nt8;
        int o = nt * 16 + lm;
        f32x4 acc = {0.f, 0.f, 0.f, 0.f};
        const bf16* br = Bp + (size_t)o * 64;
        #pragma unroll
        for (int ks = 0; ks < 2; ++ks) {
            bf16x8s bB = *(const bf16x8s*)&br[ks * 32 + quad * 8];
            acc = __builtin_amdgcn_mfma_f32_16x16x32_bf16(aX[8 + ks], bB, acc, 0, 0, 0);
        }
        int c = o >> 3, h = o & 7;
        #pragma unroll
        for (int r4 = 0; r4 < 4; ++r4) {
            int tt = t0 + quad * 4 + r4;
            int n = (b << 3) + (tt >> 7);
            int pp = ((tt & 127) << 3) | h;
            float val = siluf_(acc[r4]);
            if (sel == 0)
                vt[((size_t)n * 64 + c) * T + pp] = f2b(val);
            else
                lo[((size_t)n * T + pp) * KDIM + c] = f2b(val);
        }
    }
}

// ---------------- Kernel 3: local windowed causal attention (window 5) ----------------
__global__ __launch_bounds__(256) void k3_local(const bf16* __restrict__ lws, bf16* __restrict__ ol) {
    int wave = threadIdx.x >> 6, lane = threadIdx.x & 63;
    int ridx = blockIdx.x * 4 + wave;   // 8192 blocks -> 32768 rows
    int n = ridx >> 10, p = ridx & 1023;
    const bf16* base = lws + (size_t)n * T * KDIM;
    float lp = b2f(base[(size_t)p * KDIM + lane]);
    float lj[6], s[6];
    #pragma unroll
    for (int u = 0; u < 6; ++u) {
        int j = p - 5 + u;
        bool valid = (j >= 0);
        lj[u] = valid ? b2f(base[(size_t)j * KDIM + lane]) : 0.f;
        float d = lp * lj[u];
        d = waveSum64(d);
        s[u] = valid ? d * 0.125f : NEGBIG;
    }
    float mx = s[5];
    #pragma unroll
    for (int u = 0; u < 5; ++u) mx = fmaxf(mx, s[u]);
    float Z = 0.f, acc = 0.f;
    #pragma unroll
    for (int u = 0; u < 6; ++u) {
        float e = (s[u] <= NEGBIG) ? 0.f : __expf(s[u] - mx);
        Z += e;
        acc += e * lj[u];
    }
    ol[(size_t)(n * T + p) * KDIM + lane] = f2b(acc / Z);
}

// ---------------- Kernel 4 (MFMA, cooperative, double-buffered K/V): causal flash attention ----------------
// Block = one (n, 64-row q-tile); 4 waves x 16 q-rows; grid 512; balance swizzle (i, i+256 sum 17 tiles).
// Software pipeline: tile jt+1's K/V global loads issue BEFORE tile jt's compute; ds_writes land
// after compute; ONE barrier per iteration. og aliases q (safe: q staged to LDS first).
__global__ __launch_bounds__(256) void k4_mfma(const bf16* __restrict__ qws, const bf16* __restrict__ kws,
                                               const bf16* __restrict__ vt, bf16* __restrict__ og) {
    __shared__ __align__(16) bf16 sQ[64][72];
    __shared__ __align__(16) bf16 sK[2][64][72];
    __shared__ __align__(16) bf16 sVt[2][64][72];
    __shared__ __align__(16) bf16 sPt[4][16][76];

    int i = blockIdx.x;                  // 512 blocks
    int half = i >> 8, rem = i & 255;
    int n = rem >> 3, sub = rem & 7;
    int qt = half ? (15 - sub) : sub;
    int p0 = qt << 6;
    int tid = threadIdx.x, w = tid >> 6, lane = tid & 63;
    int lm = lane & 15, quad = lane >> 4;
    int vc = tid >> 2, vj8 = tid & 3;    // V staging coords

    // stage Q + tile 0 K/V (buffer 0), single barrier
    {
        const uint4* qg = (const uint4*)(qws + ((size_t)n * T + p0) * KDIM);
        #pragma unroll
        for (int r = 0; r < 2; ++r) { int e = tid + 256 * r; *(uint4*)&sQ[e >> 3][(e & 7) * 8] = qg[e]; }
        const uint4* kg = (const uint4*)(kws + (size_t)n * T * KDIM);
        #pragma unroll
        for (int r = 0; r < 2; ++r) { int e = tid + 256 * r; *(uint4*)&sK[0][e >> 3][(e & 7) * 8] = kg[e]; }
        const bf16* vrow = vt + ((size_t)n * 64 + vc) * T + vj8 * 16;
        *(uint4*)&sVt[0][vc][vj8 * 16]     = *(const uint4*)vrow;
        *(uint4*)&sVt[0][vc][vj8 * 16 + 8] = *(const uint4*)(vrow + 8);
    }
    __syncthreads();

    bf16x8s aQ[2];
    #pragma unroll
    for (int ks = 0; ks < 2; ++ks) aQ[ks] = *(const bf16x8s*)&sQ[w * 16 + lm][ks * 32 + quad * 8];

    f32x4 O[4];
    float m_i[4], l_i[4];
    #pragma unroll
    for (int t = 0; t < 4; ++t) { O[t][0] = 0.f; O[t][1] = 0.f; O[t][2] = 0.f; O[t][3] = 0.f; }
    #pragma unroll
    for (int r4 = 0; r4 < 4; ++r4) { m_i[r4] = NEGBIG; l_i[r4] = 0.f; }

    int prow_base = p0 + w * 16 + quad * 4;
    for (int jt = 0; jt <= qt; ++jt) {
        int j0 = jt << 6;
        int cur = jt & 1, nxt = cur ^ 1;
        bool pref = (jt < qt);
        // ---- issue next tile's global loads (latency covered by compute below) ----
        uint4 pk0, pk1, pv0, pv1;
        if (pref) {
            int j0n = j0 + 64;
            const uint4* kg = (const uint4*)(kws + ((size_t)n * T + j0n) * KDIM);
            pk0 = kg[tid]; pk1 = kg[tid + 256];
            const bf16* vrow = vt + ((size_t)n * 64 + vc) * T + j0n + vj8 * 16;
            pv0 = *(const uint4*)vrow;
            pv1 = *(const uint4*)(vrow + 8);
        }
        // ---- QK^T on current buffer ----
        f32x4 S[4];
        #pragma unroll
        for (int nt = 0; nt < 4; ++nt) {
            f32x4 acc = {0.f, 0.f, 0.f, 0.f};
            #pragma unroll
            for (int ks = 0; ks < 2; ++ks) {
                bf16x8s bK = *(const bf16x8s*)&sK[cur][nt * 16 + lm][ks * 32 + quad * 8];
                acc = __builtin_amdgcn_mfma_f32_16x16x32_bf16(aQ[ks], bK, acc, 0, 0, 0);
            }
            S[nt] = acc;
        }
        // ---- mask + online softmax ----
        float mt[4];
        #pragma unroll
        for (int r4 = 0; r4 < 4; ++r4) mt[r4] = NEGBIG;
        #pragma unroll
        for (int nt = 0; nt < 4; ++nt) {
            int jcol = j0 + nt * 16 + lm;
            #pragma unroll
            for (int r4 = 0; r4 < 4; ++r4) {
                float s = (jcol <= prow_base + r4) ? S[nt][r4] : NEGBIG;
                S[nt][r4] = s;
                mt[r4] = fmaxf(mt[r4], s);
            }
        }
        #pragma unroll
        for (int r4 = 0; r4 < 4; ++r4) {
            float v = mt[r4];
            v = fmaxf(v, __shfl_xor(v, 1)); v = fmaxf(v, __shfl_xor(v, 2));
            v = fmaxf(v, __shfl_xor(v, 4)); v = fmaxf(v, __shfl_xor(v, 8));
            mt[r4] = v;
        }
        float alpha[4], ps[4];
        #pragma unroll
        for (int r4 = 0; r4 < 4; ++r4) {
            float mnew = fmaxf(m_i[r4], mt[r4]);
            alpha[r4] = __expf(m_i[r4] - mnew);
            m_i[r4] = mnew; ps[r4] = 0.f;
        }
        #pragma unroll
        for (int nt = 0; nt < 4; ++nt) {
            #pragma unroll
            for (int r4 = 0; r4 < 4; ++r4) {
                float p = (S[nt][r4] <= NEGBIG) ? 0.f : __expf(S[nt][r4] - m_i[r4]);
                ps[r4] += p;
                sPt[w][quad * 4 + r4][nt * 16 + lm] = f2b(p);
            }
        }
        #pragma unroll
        for (int r4 = 0; r4 < 4; ++r4) {
            float v = ps[r4];
            v += __shfl_xor(v, 1); v += __shfl_xor(v, 2);
            v += __shfl_xor(v, 4); v += __shfl_xor(v, 8);
            l_i[r4] = l_i[r4] * alpha[r4] + v;
        }
        #pragma unroll
        for (int t = 0; t < 4; ++t)
            #pragma unroll
            for (int r4 = 0; r4 < 4; ++r4) O[t][r4] *= alpha[r4];
        // wave-private sPt handoff: pin write->read ordering
        __builtin_amdgcn_wave_barrier();
        // ---- PV on current buffer (diagonal skips provably-masked k-step) ----
        int ksmax = (jt == qt) ? (w >> 1) : 1;
        for (int ks = 0; ks <= ksmax; ++ks) {
            bf16x4s plo = *(const bf16x4s*)&sPt[w][lm][ks * 32 + quad * 8];
            bf16x4s phi = *(const bf16x4s*)&sPt[w][lm][ks * 32 + quad * 8 + 4];
            bf16x8s aP;
            #pragma unroll
            for (int ii = 0; ii < 4; ++ii) { aP[ii] = plo[ii]; aP[ii + 4] = phi[ii]; }
            #pragma unroll
            for (int ct = 0; ct < 4; ++ct) {
                bf16x8s bV = *(const bf16x8s*)&sVt[cur][ct * 16 + lm][ks * 32 + quad * 8];
                O[ct] = __builtin_amdgcn_mfma_f32_16x16x32_bf16(aP, bV, O[ct], 0, 0, 0);
            }
        }
        // ---- commit prefetched tile into the other buffer; one barrier ends the iteration ----
        if (pref) {
            int e0 = tid, e1 = tid + 256;
            *(uint4*)&sK[nxt][e0 >> 3][(e0 & 7) * 8] = pk0;
            *(uint4*)&sK[nxt][e1 >> 3][(e1 & 7) * 8] = pk1;
            *(uint4*)&sVt[nxt][vc][vj8 * 16]     = pv0;
            *(uint4*)&sVt[nxt][vc][vj8 * 16 + 8] = pv1;
        }
        __syncthreads();
    }
    #pragma unroll
    for (int r4 = 0; r4 < 4; ++r4) {
        int p = p0 + w * 16 + quad * 4 + r4;
        float inv = 1.f / l_i[r4];
        bf16* ob = og + ((size_t)n * T + p) * KDIM;
        #pragma unroll
        for (int t = 0; t < 4; ++t) ob[t * 16 + lm] = f2b(O[t][r4] * inv);
    }
}

// ---------------- Kernel 5 (MFMA): gate/concat + uni GEMM + LN1 + FF + LN2 ----------------
__global__ __launch_bounds__(256) void k5_mfma(const bf16* __restrict__ og, const bf16* __restrict__ olw,
        const bf16* __restrict__ uniwT, const float* __restrict__ unib, const float* __restrict__ xin,
        const float* __restrict__ ln1g, const float* __restrict__ ln1b,
        const bf16* __restrict__ ffw1T, const float* __restrict__ ffb1,
        const bf16* __restrict__ ffw2T, const float* __restrict__ ffb2,
        const float* __restrict__ ln2g, const float* __restrict__ ln2b,
        float* __restrict__ out) {
    __shared__ __align__(16) bf16 sU[16][1032];
    __shared__ float sY[16][68];
    __shared__ __align__(16) bf16 sYb[16][72];
    __shared__ __align__(16) bf16 sH[16][264];
    int blk = blockIdx.x;               // 256 blocks
    int b = blk >> 6, t0 = (blk & 63) << 4;
    int tid = threadIdx.x, w = tid >> 6, lane = tid & 63;
    int lm = lane & 15, quad = lane >> 4;

    for (int e = tid; e < 16384; e += 256) {
        int r = e >> 10, d = e & 1023;
        int hh = d >> 6, c = d & 63, hi = hh & 7;
        size_t idx = ((size_t)((b * NH + hi) * T) + t0 + r) * KDIM + c;
        float gv = b2f(og[idx]);
        float sg = sigmoidf_(gv);
        sU[r][d] = f2b((hh < 8) ? (1.f - sg) * b2f(olw[idx]) : sg * gv);
    }
    __syncthreads();

    int col = w * 16 + lm;
    f32x4 accU = {0.f, 0.f, 0.f, 0.f};
    const bf16* ur = uniwT + (size_t)col * 1024;
    #pragma unroll
    for (int ks = 0; ks < 32; ++ks) {
        bf16x8s aU = *(const bf16x8s*)&sU[lm][ks * 32 + quad * 8];
        bf16x8s bU = *(const bf16x8s*)&ur[ks * 32 + quad * 8];
        accU = __builtin_amdgcn_mfma_f32_16x16x32_bf16(aU, bU, accU, 0, 0, 0);
    }
    float ub = unib[col];
    #pragma unroll
    for (int r4 = 0; r4 < 4; ++r4) {
        int row = quad * 4 + r4;
        float a = siluf_(accU[r4] + ub);
        sY[row][col] = a + xin[((size_t)(b * T) + t0 + row) * KDIM + col];
    }
    __syncthreads();

    #pragma unroll
    for (int i = 0; i < 4; ++i) {
        int row = w + 4 * i;
        float yv = sY[row][lane];
        float mean = waveSum64(yv) * (1.f / 64.f);
        float dv = yv - mean;
        float var = waveSum64(dv * dv) * (1.f / 64.f);
        float y = dv * rsqrtf(var + 1e-5f) * ln1g[lane] + ln1b[lane];
        sY[row][lane] = y;
        sYb[row][lane] = f2b(y);
    }
    __syncthreads();

    bf16x8s aY[2];
    #pragma unroll
    for (int ks = 0; ks < 2; ++ks) aY[ks] = *(const bf16x8s*)&sYb[lm][ks * 32 + quad * 8];
    #pragma unroll
    for (int u = 0; u < 4; ++u) {
        int j = (w * 4 + u) * 16 + lm;
        f32x4 acc = {0.f, 0.f, 0.f, 0.f};
        const bf16* fr = ffw1T + (size_t)j * 64;
        #pragma unroll
        for (int ks = 0; ks < 2; ++ks) {
            bf16x8s bF = *(const bf16x8s*)&fr[ks * 32 + quad * 8];
            acc = __builtin_amdgcn_mfma_f32_16x16x32_bf16(aY[ks], bF, acc, 0, 0, 0);
        }
        float b1 = ffb1[j];
        #pragma unroll
        for (int r4 = 0; r4 < 4; ++r4)
            sH[quad * 4 + r4][j] = f2b(fmaxf(acc[r4] + b1, 0.f));
    }
    __syncthreads();

    f32x4 accF = {0.f, 0.f, 0.f, 0.f};
    const bf16* f2r = ffw2T + (size_t)col * 256;
    #pragma unroll
    for (int ks = 0; ks < 8; ++ks) {
        bf16x8s aH = *(const bf16x8s*)&sH[lm][ks * 32 + quad * 8];
        bf16x8s bF2 = *(const bf16x8s*)&f2r[ks * 32 + quad * 8];
        accF = __builtin_amdgcn_mfma_f32_16x16x32_bf16(aH, bF2, accF, 0, 0, 0);
    }
    float b2 = ffb2[col];
    #pragma unroll
    for (int r4 = 0; r4 < 4; ++r4) {
        int row = quad * 4 + r4;
        sY[row][col] = (accF[r4] + b2) + sY[row][col];
    }
    __syncthreads();

    #pragma unroll
    for (int i = 0; i < 4; ++i) {
        int row = w + 4 * i;
        float z = sY[row][lane];
        float mean = waveSum64(z) * (1.f / 64.f);
        float dv = z - mean;
        float var = waveSum64(dv * dv) * (1.f / 64.f);
        out[((size_t)(b * T) + t0 + row) * KDIM + lane] =
            dv * rsqrtf(var + 1e-5f) * ln2g[lane] + ln2b[lane];
    }
}

extern "C" void kernel_launch(void* const* d_in, const int* in_sizes, int n_in,
                              void* d_out, int out_size, void* d_ws, size_t ws_size,
                              hipStream_t stream) {
    (void)in_sizes; (void)n_in; (void)out_size; (void)ws_size;
    const float* x    = (const float*)d_in[0];
    const float* sqw  = (const float*)d_in[1];
    const float* bng  = (const float*)d_in[2];
    const float* bnb  = (const float*)d_in[3];
    const float* dww  = (const float*)d_in[4];
    const float* exw  = (const float*)d_in[5];
    const float* pos  = (const float*)d_in[6];
    const float* wq   = (const float*)d_in[7];
    const float* bq   = (const float*)d_in[8];
    const float* wk   = (const float*)d_in[9];
    const float* bk   = (const float*)d_in[10];
    const float* wv   = (const float*)d_in[11];
    const float* wl   = (const float*)d_in[12];
    const float* uniw = (const float*)d_in[13];
    const float* unib = (const float*)d_in[14];
    const float* ln1g = (const float*)d_in[15];
    const float* ln1b = (const float*)d_in[16];
    const float* ln2g = (const float*)d_in[17];
    const float* ln2b = (const float*)d_in[18];
    const float* ffw1 = (const float*)d_in[19];
    const float* ffb1 = (const float*)d_in[20];
    const float* ffw2 = (const float*)d_in[21];
    const float* ffb2 = (const float*)d_in[22];

    // ws layout — ~22.5 MiB.
    char* ws = (char*)d_ws;
    float* xin   = (float*)(ws);                  // fp32 1.0 MiB
    bf16*  qog   = (bf16*)(ws + 0x100000);        // 4 MiB  q, then og in-place
    bf16*  kw_   = (bf16*)(ws + 0x500000);        // 4 MiB
    bf16*  vtw   = (bf16*)(ws + 0x900000);        // 4 MiB  (transposed v)
    bf16*  lw_   = (bf16*)(ws + 0xD00000);        // 4 MiB
    bf16*  olw   = (bf16*)(ws + 0x1100000);       // 4 MiB
    float* x3    = (float*)(ws + 0x1500000);      // fp32 0.5 MiB
    bf16*  BqT   = (bf16*)(ws + 0x1580000);       // 320 KiB
    bf16*  BkT   = (bf16*)(ws + 0x15D0000);       // 320 KiB
    bf16*  BvT   = (bf16*)(ws + 0x1620000);       // 64 KiB
    bf16*  BlT   = (bf16*)(ws + 0x1630000);       // 64 KiB
    bf16*  uniwT = (bf16*)(ws + 0x1640000);       // 128 KiB
    bf16*  ffw1T = (bf16*)(ws + 0x1660000);       // 32 KiB
    bf16*  ffw2T = (bf16*)(ws + 0x1668000);       // 32 KiB (end 0x1670000)

    k1a_x3 <<<512, 256, 0, stream>>>(x, sqw, bng, bnb, wq, wk, wv, wl, uniw, ffw1, ffw2,
                                     x3, BqT, BkT, BvT, BlT, uniwT, ffw1T, ffw2T);
    k1b_xin<<<512, 256, 0, stream>>>(x3, dww, exw, x, pos, xin);
    k2_mfma<<<512, 256, 0, stream>>>(xin, BqT, BkT, BvT, BlT, bq, bk, qog, kw_, vtw, lw_);
    k3_local<<<8192, 256, 0, stream>>>(lw_, olw);
    k4_mfma<<<512, 256, 0, stream>>>(qog, kw_, vtw, qog);   // og overwrites q in-place
    k5_mfma<<<256, 256, 0, stream>>>(qog, olw, uniwT, unib, xin,
                                     ln1g, ln1b, ffw1T, ffb1, ffw2T, ffb2, ln2g, ln2b,
                                     (float*)d_out);
}

// Round 17
// 210.934 us; speedup vs baseline: 1.3173x; 1.1052x over previous
//
#include <hip/hip_runtime.h>
#include <hip/hip_bf16.h>
#include <math.h>

#define B 4
#define T 1024
#define KDIM 64
#define R 32
#define NH 8
#define NEGBIG (-1e30f)

typedef __hip_bfloat16 bf16;
typedef __attribute__((ext_vector_type(8))) short bf16x8s;
typedef __attribute__((ext_vector_type(4))) short bf16x4s;
typedef __attribute__((ext_vector_type(4))) float f32x4;

static __device__ __forceinline__ float b2f(bf16 x) { return __bfloat162float(x); }
static __device__ __forceinline__ bf16 f2b(float x) { return __float2bfloat16(x); }
static __device__ __forceinline__ float sigmoidf_(float x) { return 1.0f / (1.0f + __expf(-x)); }
static __device__ __forceinline__ float siluf_(float x) { return x * sigmoidf_(x); }

static __device__ __forceinline__ float waveSum64(float v) {
    #pragma unroll
    for (int m = 32; m >= 1; m >>= 1) v += __shfl_xor(v, m);
    return v;
}

union bf8u { bf16x8s v; bf16 a[8]; };

// ---------------- Kernel 1a: x3 = bn(squeeze conv)  +  fused weight prep ----------------
__global__ __launch_bounds__(256) void k1a_x3(const float* __restrict__ x, const float* __restrict__ sqw,
                                              const float* __restrict__ bng, const float* __restrict__ bnb,
                                              const float* __restrict__ wq, const float* __restrict__ wk,
                                              const float* __restrict__ wv, const float* __restrict__ wl,
                                              const float* __restrict__ uniw, const float* __restrict__ ffw1,
                                              const float* __restrict__ ffw2,
                                              float* __restrict__ x3,
                                              bf16* __restrict__ BqT, bf16* __restrict__ BkT,
                                              bf16* __restrict__ BvT, bf16* __restrict__ BlT,
                                              bf16* __restrict__ uniwT, bf16* __restrict__ ffw1T,
                                              bf16* __restrict__ ffw2T) {
    int blk = blockIdx.x;               // 512 blocks
    int b = blk >> 7, t0 = (blk & 127) << 3;
    int row = threadIdx.x >> 5, o = threadIdx.x & 31;
    int tt = t0 + row;
    const float* xr = x + (size_t)(b * T + tt) * KDIM;
    const float* wr = sqw + o * KDIM;
    float acc = 0.f;
    #pragma unroll
    for (int i = 0; i < KDIM; ++i) acc += xr[i] * wr[i];
    const float inv = 0.9999950000374997f; // 1/sqrt(1+1e-5)
    x3[(size_t)(b * T + tt) * R + o] = bng[o] * acc * inv + bnb[o];

    int gid = blk * 256 + threadIdx.x;
    // conv weights, s-major K (read-coalesced)
    #pragma unroll
    for (int rep = 0; rep < 3; ++rep) {
        int e = gid + rep * 131072;
        if (e < 163840) {
            int oo = e / 320, rem = e - oo * 320;
            int i = rem / 5, s = rem - i * 5;
            BqT[oo * 320 + s * 64 + i] = f2b(wq[e]);
        } else if (e < 327680) {
            int e2 = e - 163840;
            int oo = e2 / 320, rem = e2 - oo * 320;
            int i = rem / 5, s = rem - i * 5;
            BkT[oo * 320 + s * 64 + i] = f2b(wk[e2]);
        } else if (e < 360448) {
            int e3 = e - 327680;
            BvT[e3] = f2b(wv[e3]);
        } else {
            int e4 = e - 360448;
            BlT[e4] = f2b(wl[e4]);
        }
    }
    // epilogue weights (read-coalesced): uniwT[c][d], ffw1T[j][i], ffw2T[c][j]
    {
        int e = gid;
        if (e < 65536) {
            int d = e >> 6, c = e & 63;
            uniwT[c * 1024 + d] = f2b(uniw[e]);
        } else if (e < 81920) {
            int e2 = e - 65536;
            int i = e2 >> 8, j = e2 & 255;
            ffw1T[j * 64 + i] = f2b(ffw1[e2]);
        } else if (e < 98304) {
            int e3 = e - 81920;
            int j = e3 >> 6, c = e3 & 63;
            ffw2T[c * 256 + j] = f2b(ffw2[e3]);
        }
    }
}

// ---------------- Kernel 1b: depthwise diff + excite conv + gate + pos ----------------
__global__ __launch_bounds__(256) void k1b_xin(const float* __restrict__ x3, const float* __restrict__ dww,
                                               const float* __restrict__ exw, const float* __restrict__ x,
                                               const float* __restrict__ pos, float* __restrict__ xin) {
    __shared__ float sx3[10 * R];
    __shared__ float sxp[8 * R];
    int blk = blockIdx.x;               // 512 blocks
    int b = blk >> 7, t0 = (blk & 127) << 3;
    int tid = threadIdx.x;
    for (int e = tid; e < 320; e += 256) {
        int rr = e >> 5, o = e & 31;
        int tt = t0 + rr;
        sx3[e] = (tt < T) ? x3[(size_t)(b * T + tt) * R + o] : 0.f;
    }
    __syncthreads();
    {
        int rr = tid >> 5, o = tid & 31;
        int tt = t0 + rr;
        float v;
        if (tt == T - 1) {
            v = sx3[rr * R + o];
        } else {
            float w0 = dww[o * 3 + 0], w1 = dww[o * 3 + 1], w2 = dww[o * 3 + 2];
            v = sx3[rr * R + o] * (w0 - 1.f) + sx3[(rr + 1) * R + o] * w1 + sx3[(rr + 2) * R + o] * w2;
        }
        sxp[rr * R + o] = v;
    }
    __syncthreads();
    int rr = tid >> 5, c0 = tid & 31;
    int tt = t0 + rr;
    #pragma unroll
    for (int u = 0; u < 2; ++u) {
        int c = c0 + u * 32;
        const float* ew = exw + c * R;
        float g = 0.f;
        #pragma unroll
        for (int o = 0; o < R; ++o) g += ew[o] * sxp[rr * R + o];
        float sg = sigmoidf_(g);
        size_t idx = (size_t)(b * T + tt) * KDIM + c;
        xin[idx] = x[idx] * sg + pos[tt * KDIM + c];
    }
}

// ---------------- Kernel 2 (MFMA): q/k/v/l convs + silu + head-scramble store ----------------
__global__ __launch_bounds__(256) void k2_mfma(const float* __restrict__ xin,
        const bf16* __restrict__ BqT, const bf16* __restrict__ BkT,
        const bf16* __restrict__ BvT, const bf16* __restrict__ BlT,
        const float* __restrict__ bq, const float* __restrict__ bk,
        bf16* __restrict__ qo, bf16* __restrict__ ko, bf16* __restrict__ vt, bf16* __restrict__ lo) {
    __shared__ __align__(16) bf16 sX[24][72];
    int blk = blockIdx.x;               // 512 blocks
    int sel = blk >> 8;                 // 0: q+v, 1: k+l
    int b = (blk >> 6) & 3, t0 = (blk & 63) << 4;
    int tid = threadIdx.x, w = tid >> 6, lane = tid & 63;
    int lm = lane & 15, quad = lane >> 4;

    for (int e = tid; e < 1536; e += 256) {
        int rr = e >> 6, ch = e & 63;
        int t = t0 - 8 + rr;
        sX[rr][ch] = f2b((t >= 0) ? xin[((size_t)(b * T) + t) * KDIM + ch] : 0.f);
    }
    __syncthreads();

    bf16x8s aX[10];
    #pragma unroll
    for (int ks = 0; ks < 10; ++ks)
        aX[ks] = *(const bf16x8s*)&sX[lm + 2 * (ks >> 1)][(ks & 1) * 32 + quad * 8];

    const bf16* Bd = sel ? BkT : BqT;
    const float* bias = sel ? bk : bq;
    const bf16* Bp = sel ? BlT : BvT;
    bf16* OutD = sel ? ko : qo;
    const float isg = 0.35355339059327373f; // 1/64^0.25

    for (int nt8 = 0; nt8 < 8; ++nt8) {
        int nt = w * 8 + nt8;
        int o = nt * 16 + lm;
        f32x4 acc = {0.f, 0.f, 0.f, 0.f};
        const bf16* br = Bd + (size_t)o * 320;
        #pragma unroll
        for (int ks = 0; ks < 10; ++ks) {
            bf16x8s bB = *(const bf16x8s*)&br[ks * 32 + quad * 8];
            acc = __builtin_amdgcn_mfma_f32_16x16x32_bf16(aX[ks], bB, acc, 0, 0, 0);
        }
        float bb = bias[o];
        int c = o >> 3, h = o & 7;
        #pragma unroll
        for (int r4 = 0; r4 < 4; ++r4) {
            int tt = t0 + quad * 4 + r4;
            int n = (b << 3) + (tt >> 7);
            int pp = ((tt & 127) << 3) | h;
            OutD[((size_t)n * T + pp) * KDIM + c] = f2b(siluf_(acc[r4] + bb) * isg);
        }
    }
    for (int nt8 = 0; nt8 < 8; ++nt8) {
        int nt = w * 8 + nt8;
        int o = nt * 16 + lm;
        f32x4 acc = {0.f, 0.f, 0.f, 0.f};
        const bf16* br = Bp + (size_t)o * 64;
        #pragma unroll
        for (int ks = 0; ks < 2; ++ks) {
            bf16x8s bB = *(const bf16x8s*)&br[ks * 32 + quad * 8];
            acc = __builtin_amdgcn_mfma_f32_16x16x32_bf16(aX[8 + ks], bB, acc, 0, 0, 0);
        }
        int c = o >> 3, h = o & 7;
        #pragma unroll
        for (int r4 = 0; r4 < 4; ++r4) {
            int tt = t0 + quad * 4 + r4;
            int n = (b << 3) + (tt >> 7);
            int pp = ((tt & 127) << 3) | h;
            float val = siluf_(acc[r4]);
            if (sel == 0)
                vt[((size_t)n * 64 + c) * T + pp] = f2b(val);
            else
                lo[((size_t)n * T + pp) * KDIM + c] = f2b(val);
        }
    }
}

// ---------------- Kernel 3: local windowed causal attention (window 5) ----------------
__global__ __launch_bounds__(256) void k3_local(const bf16* __restrict__ lws, bf16* __restrict__ ol) {
    int wave = threadIdx.x >> 6, lane = threadIdx.x & 63;
    int ridx = blockIdx.x * 4 + wave;   // 8192 blocks -> 32768 rows
    int n = ridx >> 10, p = ridx & 1023;
    const bf16* base = lws + (size_t)n * T * KDIM;
    float lp = b2f(base[(size_t)p * KDIM + lane]);
    float lj[6], s[6];
    #pragma unroll
    for (int u = 0; u < 6; ++u) {
        int j = p - 5 + u;
        bool valid = (j >= 0);
        lj[u] = valid ? b2f(base[(size_t)j * KDIM + lane]) : 0.f;
        float d = lp * lj[u];
        d = waveSum64(d);
        s[u] = valid ? d * 0.125f : NEGBIG;
    }
    float mx = s[5];
    #pragma unroll
    for (int u = 0; u < 5; ++u) mx = fmaxf(mx, s[u]);
    float Z = 0.f, acc = 0.f;
    #pragma unroll
    for (int u = 0; u < 6; ++u) {
        float e = (s[u] <= NEGBIG) ? 0.f : __expf(s[u] - mx);
        Z += e;
        acc += e * lj[u];
    }
    ol[(size_t)(n * T + p) * KDIM + lane] = f2b(acc / Z);
}

// ---------------- Kernel 4 (MFMA, cooperative, double-buffered K/V): causal flash attention ----------------
__global__ __launch_bounds__(256) void k4_mfma(const bf16* __restrict__ qws, const bf16* __restrict__ kws,
                                               const bf16* __restrict__ vt, bf16* __restrict__ og) {
    __shared__ __align__(16) bf16 sQ[64][72];
    __shared__ __align__(16) bf16 sK[2][64][72];
    __shared__ __align__(16) bf16 sVt[2][64][72];
    __shared__ __align__(16) bf16 sPt[4][16][76];

    int i = blockIdx.x;                  // 512 blocks
    int half = i >> 8, rem = i & 255;
    int n = rem >> 3, sub = rem & 7;
    int qt = half ? (15 - sub) : sub;
    int p0 = qt << 6;
    int tid = threadIdx.x, w = tid >> 6, lane = tid & 63;
    int lm = lane & 15, quad = lane >> 4;
    int vc = tid >> 2, vj8 = tid & 3;    // V staging coords

    {
        const uint4* qg = (const uint4*)(qws + ((size_t)n * T + p0) * KDIM);
        #pragma unroll
        for (int r = 0; r < 2; ++r) { int e = tid + 256 * r; *(uint4*)&sQ[e >> 3][(e & 7) * 8] = qg[e]; }
        const uint4* kg = (const uint4*)(kws + (size_t)n * T * KDIM);
        #pragma unroll
        for (int r = 0; r < 2; ++r) { int e = tid + 256 * r; *(uint4*)&sK[0][e >> 3][(e & 7) * 8] = kg[e]; }
        const bf16* vrow = vt + ((size_t)n * 64 + vc) * T + vj8 * 16;
        *(uint4*)&sVt[0][vc][vj8 * 16]     = *(const uint4*)vrow;
        *(uint4*)&sVt[0][vc][vj8 * 16 + 8] = *(const uint4*)(vrow + 8);
    }
    __syncthreads();

    bf16x8s aQ[2];
    #pragma unroll
    for (int ks = 0; ks < 2; ++ks) aQ[ks] = *(const bf16x8s*)&sQ[w * 16 + lm][ks * 32 + quad * 8];

    f32x4 O[4];
    float m_i[4], l_i[4];
    #pragma unroll
    for (int t = 0; t < 4; ++t) { O[t][0] = 0.f; O[t][1] = 0.f; O[t][2] = 0.f; O[t][3] = 0.f; }
    #pragma unroll
    for (int r4 = 0; r4 < 4; ++r4) { m_i[r4] = NEGBIG; l_i[r4] = 0.f; }

    int prow_base = p0 + w * 16 + quad * 4;
    for (int jt = 0; jt <= qt; ++jt) {
        int j0 = jt << 6;
        int cur = jt & 1, nxt = cur ^ 1;
        bool pref = (jt < qt);
        uint4 pk0, pk1, pv0, pv1;
        if (pref) {
            int j0n = j0 + 64;
            const uint4* kg = (const uint4*)(kws + ((size_t)n * T + j0n) * KDIM);
            pk0 = kg[tid]; pk1 = kg[tid + 256];
            const bf16* vrow = vt + ((size_t)n * 64 + vc) * T + j0n + vj8 * 16;
            pv0 = *(const uint4*)vrow;
            pv1 = *(const uint4*)(vrow + 8);
        }
        f32x4 S[4];
        #pragma unroll
        for (int nt = 0; nt < 4; ++nt) {
            f32x4 acc = {0.f, 0.f, 0.f, 0.f};
            #pragma unroll
            for (int ks = 0; ks < 2; ++ks) {
                bf16x8s bK = *(const bf16x8s*)&sK[cur][nt * 16 + lm][ks * 32 + quad * 8];
                acc = __builtin_amdgcn_mfma_f32_16x16x32_bf16(aQ[ks], bK, acc, 0, 0, 0);
            }
            S[nt] = acc;
        }
        float mt[4];
        #pragma unroll
        for (int r4 = 0; r4 < 4; ++r4) mt[r4] = NEGBIG;
        #pragma unroll
        for (int nt = 0; nt < 4; ++nt) {
            int jcol = j0 + nt * 16 + lm;
            #pragma unroll
            for (int r4 = 0; r4 < 4; ++r4) {
                float s = (jcol <= prow_base + r4) ? S[nt][r4] : NEGBIG;
                S[nt][r4] = s;
                mt[r4] = fmaxf(mt[r4], s);
            }
        }
        #pragma unroll
        for (int r4 = 0; r4 < 4; ++r4) {
            float v = mt[r4];
            v = fmaxf(v, __shfl_xor(v, 1)); v = fmaxf(v, __shfl_xor(v, 2));
            v = fmaxf(v, __shfl_xor(v, 4)); v = fmaxf(v, __shfl_xor(v, 8));
            mt[r4] = v;
        }
        float alpha[4], ps[4];
        #pragma unroll
        for (int r4 = 0; r4 < 4; ++r4) {
            float mnew = fmaxf(m_i[r4], mt[r4]);
            alpha[r4] = __expf(m_i[r4] - mnew);
            m_i[r4] = mnew; ps[r4] = 0.f;
        }
        #pragma unroll
        for (int nt = 0; nt < 4; ++nt) {
            #pragma unroll
            for (int r4 = 0; r4 < 4; ++r4) {
                float p = (S[nt][r4] <= NEGBIG) ? 0.f : __expf(S[nt][r4] - m_i[r4]);
                ps[r4] += p;
                sPt[w][quad * 4 + r4][nt * 16 + lm] = f2b(p);
            }
        }
        #pragma unroll
        for (int r4 = 0; r4 < 4; ++r4) {
            float v = ps[r4];
            v += __shfl_xor(v, 1); v += __shfl_xor(v, 2);
            v += __shfl_xor(v, 4); v += __shfl_xor(v, 8);
            l_i[r4] = l_i[r4] * alpha[r4] + v;
        }
        #pragma unroll
        for (int t = 0; t < 4; ++t)
            #pragma unroll
            for (int r4 = 0; r4 < 4; ++r4) O[t][r4] *= alpha[r4];
        __builtin_amdgcn_wave_barrier();
        int ksmax = (jt == qt) ? (w >> 1) : 1;
        for (int ks = 0; ks <= ksmax; ++ks) {
            bf16x4s plo = *(const bf16x4s*)&sPt[w][lm][ks * 32 + quad * 8];
            bf16x4s phi = *(const bf16x4s*)&sPt[w][lm][ks * 32 + quad * 8 + 4];
            bf16x8s aP;
            #pragma unroll
            for (int ii = 0; ii < 4; ++ii) { aP[ii] = plo[ii]; aP[ii + 4] = phi[ii]; }
            #pragma unroll
            for (int ct = 0; ct < 4; ++ct) {
                bf16x8s bV = *(const bf16x8s*)&sVt[cur][ct * 16 + lm][ks * 32 + quad * 8];
                O[ct] = __builtin_amdgcn_mfma_f32_16x16x32_bf16(aP, bV, O[ct], 0, 0, 0);
            }
        }
        if (pref) {
            int e0 = tid, e1 = tid + 256;
            *(uint4*)&sK[nxt][e0 >> 3][(e0 & 7) * 8] = pk0;
            *(uint4*)&sK[nxt][e1 >> 3][(e1 & 7) * 8] = pk1;
            *(uint4*)&sVt[nxt][vc][vj8 * 16]     = pv0;
            *(uint4*)&sVt[nxt][vc][vj8 * 16 + 8] = pv1;
        }
        __syncthreads();
    }
    #pragma unroll
    for (int r4 = 0; r4 < 4; ++r4) {
        int p = p0 + w * 16 + quad * 4 + r4;
        float inv = 1.f / l_i[r4];
        bf16* ob = og + ((size_t)n * T + p) * KDIM;
        #pragma unroll
        for (int t = 0; t < 4; ++t) ob[t * 16 + lm] = f2b(O[t][r4] * inv);
    }
}

// ---------------- Kernel 5 (MFMA): gate/concat + uni GEMM + LN1 + FF + LN2 ----------------
// R17: staging vectorized (bf16x8 loads of og/olw) — math identical to scalar version.
__global__ __launch_bounds__(256) void k5_mfma(const bf16* __restrict__ og, const bf16* __restrict__ olw,
        const bf16* __restrict__ uniwT, const float* __restrict__ unib, const float* __restrict__ xin,
        const float* __restrict__ ln1g, const float* __restrict__ ln1b,
        const bf16* __restrict__ ffw1T, const float* __restrict__ ffb1,
        const bf16* __restrict__ ffw2T, const float* __restrict__ ffb2,
        const float* __restrict__ ln2g, const float* __restrict__ ln2b,
        float* __restrict__ out) {
    __shared__ __align__(16) bf16 sU[16][1032];
    __shared__ float sY[16][68];
    __shared__ __align__(16) bf16 sYb[16][72];
    __shared__ __align__(16) bf16 sH[16][264];
    int blk = blockIdx.x;               // 256 blocks
    int b = blk >> 6, t0 = (blk & 63) << 4;
    int tid = threadIdx.x, w = tid >> 6, lane = tid & 63;
    int lm = lane & 15, quad = lane >> 4;

    // ---- gated-concat staging: 2048 vec8 slots (16 rows x 16 hh x 8 segs) ----
    #pragma unroll
    for (int it = 0; it < 8; ++it) {
        int e = tid + it * 256;
        int r = e >> 7, dd = e & 127;
        int hh = dd >> 3, cs = dd & 7;
        int hi = hh & 7;
        size_t rowoff = ((size_t)((b * NH + hi) * T) + t0 + r) * KDIM + cs * 8;
        bf8u gv; gv.v = *(const bf16x8s*)(og + rowoff);
        bf8u res;
        if (hh < 8) {
            bf8u lv; lv.v = *(const bf16x8s*)(olw + rowoff);
            #pragma unroll
            for (int k = 0; k < 8; ++k) {
                float g = b2f(gv.a[k]);
                res.a[k] = f2b((1.f - sigmoidf_(g)) * b2f(lv.a[k]));
            }
        } else {
            #pragma unroll
            for (int k = 0; k < 8; ++k) {
                float g = b2f(gv.a[k]);
                res.a[k] = f2b(sigmoidf_(g) * g);
            }
        }
        *(bf16x8s*)&sU[r][hh * 64 + cs * 8] = res.v;
    }
    __syncthreads();

    int col = w * 16 + lm;
    f32x4 accU = {0.f, 0.f, 0.f, 0.f};
    const bf16* ur = uniwT + (size_t)col * 1024;
    #pragma unroll
    for (int ks = 0; ks < 32; ++ks) {
        bf16x8s aU = *(const bf16x8s*)&sU[lm][ks * 32 + quad * 8];
        bf16x8s bU = *(const bf16x8s*)&ur[ks * 32 + quad * 8];
        accU = __builtin_amdgcn_mfma_f32_16x16x32_bf16(aU, bU, accU, 0, 0, 0);
    }
    float ub = unib[col];
    #pragma unroll
    for (int r4 = 0; r4 < 4; ++r4) {
        int row = quad * 4 + r4;
        float a = siluf_(accU[r4] + ub);
        sY[row][col] = a + xin[((size_t)(b * T) + t0 + row) * KDIM + col];
    }
    __syncthreads();

    #pragma unroll
    for (int i = 0; i < 4; ++i) {
        int row = w + 4 * i;
        float yv = sY[row][lane];
        float mean = waveSum64(yv) * (1.f / 64.f);
        float dv = yv - mean;
        float var = waveSum64(dv * dv) * (1.f / 64.f);
        float y = dv * rsqrtf(var + 1e-5f) * ln1g[lane] + ln1b[lane];
        sY[row][lane] = y;
        sYb[row][lane] = f2b(y);
    }
    __syncthreads();

    bf16x8s aY[2];
    #pragma unroll
    for (int ks = 0; ks < 2; ++ks) aY[ks] = *(const bf16x8s*)&sYb[lm][ks * 32 + quad * 8];
    #pragma unroll
    for (int u = 0; u < 4; ++u) {
        int j = (w * 4 + u) * 16 + lm;
        f32x4 acc = {0.f, 0.f, 0.f, 0.f};
        const bf16* fr = ffw1T + (size_t)j * 64;
        #pragma unroll
        for (int ks = 0; ks < 2; ++ks) {
            bf16x8s bF = *(const bf16x8s*)&fr[ks * 32 + quad * 8];
            acc = __builtin_amdgcn_mfma_f32_16x16x32_bf16(aY[ks], bF, acc, 0, 0, 0);
        }
        float b1 = ffb1[j];
        #pragma unroll
        for (int r4 = 0; r4 < 4; ++r4)
            sH[quad * 4 + r4][j] = f2b(fmaxf(acc[r4] + b1, 0.f));
    }
    __syncthreads();

    f32x4 accF = {0.f, 0.f, 0.f, 0.f};
    const bf16* f2r = ffw2T + (size_t)col * 256;
    #pragma unroll
    for (int ks = 0; ks < 8; ++ks) {
        bf16x8s aH = *(const bf16x8s*)&sH[lm][ks * 32 + quad * 8];
        bf16x8s bF2 = *(const bf16x8s*)&f2r[ks * 32 + quad * 8];
        accF = __builtin_amdgcn_mfma_f32_16x16x32_bf16(aH, bF2, accF, 0, 0, 0);
    }
    float b2 = ffb2[col];
    #pragma unroll
    for (int r4 = 0; r4 < 4; ++r4) {
        int row = quad * 4 + r4;
        sY[row][col] = (accF[r4] + b2) + sY[row][col];
    }
    __syncthreads();

    #pragma unroll
    for (int i = 0; i < 4; ++i) {
        int row = w + 4 * i;
        float z = sY[row][lane];
        float mean = waveSum64(z) * (1.f / 64.f);
        float dv = z - mean;
        float var = waveSum64(dv * dv) * (1.f / 64.f);
        out[((size_t)(b * T) + t0 + row) * KDIM + lane] =
            dv * rsqrtf(var + 1e-5f) * ln2g[lane] + ln2b[lane];
    }
}

extern "C" void kernel_launch(void* const* d_in, const int* in_sizes, int n_in,
                              void* d_out, int out_size, void* d_ws, size_t ws_size,
                              hipStream_t stream) {
    (void)in_sizes; (void)n_in; (void)out_size; (void)ws_size;
    const float* x    = (const float*)d_in[0];
    const float* sqw  = (const float*)d_in[1];
    const float* bng  = (const float*)d_in[2];
    const float* bnb  = (const float*)d_in[3];
    const float* dww  = (const float*)d_in[4];
    const float* exw  = (const float*)d_in[5];
    const float* pos  = (const float*)d_in[6];
    const float* wq   = (const float*)d_in[7];
    const float* bq   = (const float*)d_in[8];
    const float* wk   = (const float*)d_in[9];
    const float* bk   = (const float*)d_in[10];
    const float* wv   = (const float*)d_in[11];
    const float* wl   = (const float*)d_in[12];
    const float* uniw = (const float*)d_in[13];
    const float* unib = (const float*)d_in[14];
    const float* ln1g = (const float*)d_in[15];
    const float* ln1b = (const float*)d_in[16];
    const float* ln2g = (const float*)d_in[17];
    const float* ln2b = (const float*)d_in[18];
    const float* ffw1 = (const float*)d_in[19];
    const float* ffb1 = (const float*)d_in[20];
    const float* ffw2 = (const float*)d_in[21];
    const float* ffb2 = (const float*)d_in[22];

    // ws layout — ~22.5 MiB.
    char* ws = (char*)d_ws;
    float* xin   = (float*)(ws);                  // fp32 1.0 MiB
    bf16*  qog   = (bf16*)(ws + 0x100000);        // 4 MiB  q, then og in-place
    bf16*  kw_   = (bf16*)(ws + 0x500000);        // 4 MiB
    bf16*  vtw   = (bf16*)(ws + 0x900000);        // 4 MiB  (transposed v)
    bf16*  lw_   = (bf16*)(ws + 0xD00000);        // 4 MiB
    bf16*  olw   = (bf16*)(ws + 0x1100000);       // 4 MiB
    float* x3    = (float*)(ws + 0x1500000);      // fp32 0.5 MiB
    bf16*  BqT   = (bf16*)(ws + 0x1580000);       // 320 KiB
    bf16*  BkT   = (bf16*)(ws + 0x15D0000);       // 320 KiB
    bf16*  BvT   = (bf16*)(ws + 0x1620000);       // 64 KiB
    bf16*  BlT   = (bf16*)(ws + 0x1630000);       // 64 KiB
    bf16*  uniwT = (bf16*)(ws + 0x1640000);       // 128 KiB
    bf16*  ffw1T = (bf16*)(ws + 0x1660000);       // 32 KiB
    bf16*  ffw2T = (bf16*)(ws + 0x1668000);       // 32 KiB (end 0x1670000)

    k1a_x3 <<<512, 256, 0, stream>>>(x, sqw, bng, bnb, wq, wk, wv, wl, uniw, ffw1, ffw2,
                                     x3, BqT, BkT, BvT, BlT, uniwT, ffw1T, ffw2T);
    k1b_xin<<<512, 256, 0, stream>>>(x3, dww, exw, x, pos, xin);
    k2_mfma<<<512, 256, 0, stream>>>(xin, BqT, BkT, BvT, BlT, bq, bk, qog, kw_, vtw, lw_);
    k3_local<<<8192, 256, 0, stream>>>(lw_, olw);
    k4_mfma<<<512, 256, 0, stream>>>(qog, kw_, vtw, qog);   // og overwrites q in-place
    k5_mfma<<<256, 256, 0, stream>>>(qog, olw, uniwT, unib, xin,
                                     ln1g, ln1b, ffw1T, ffb1, ffw2T, ffb2, ln2g, ln2b,
                                     (float*)d_out);
}

// Round 18
// 198.872 us; speedup vs baseline: 1.3972x; 1.0607x over previous
//
#include <hip/hip_runtime.h>
#include <hip/hip_bf16.h>
#include <math.h>

#define B 4
#define T 1024
#define KDIM 64
#define R 32
#define NH 8
#define NEGBIG (-1e30f)

typedef __hip_bfloat16 bf16;
typedef __attribute__((ext_vector_type(8))) short bf16x8s;
typedef __attribute__((ext_vector_type(4))) short bf16x4s;
typedef __attribute__((ext_vector_type(4))) float f32x4;

static __device__ __forceinline__ float b2f(bf16 x) { return __bfloat162float(x); }
static __device__ __forceinline__ bf16 f2b(float x) { return __float2bfloat16(x); }
static __device__ __forceinline__ float sigmoidf_(float x) { return 1.0f / (1.0f + __expf(-x)); }
static __device__ __forceinline__ float siluf_(float x) { return x * sigmoidf_(x); }

static __device__ __forceinline__ float waveSum64(float v) {
    #pragma unroll
    for (int m = 32; m >= 1; m >>= 1) v += __shfl_xor(v, m);
    return v;
}

union bf8u { bf16x8s v; bf16 a[8]; };

// ---------------- Kernel 1a: x3 = bn(squeeze conv)  +  fused weight prep ----------------
__global__ __launch_bounds__(256) void k1a_x3(const float* __restrict__ x, const float* __restrict__ sqw,
                                              const float* __restrict__ bng, const float* __restrict__ bnb,
                                              const float* __restrict__ wq, const float* __restrict__ wk,
                                              const float* __restrict__ wv, const float* __restrict__ wl,
                                              const float* __restrict__ uniw, const float* __restrict__ ffw1,
                                              const float* __restrict__ ffw2,
                                              float* __restrict__ x3,
                                              bf16* __restrict__ BqT, bf16* __restrict__ BkT,
                                              bf16* __restrict__ BvT, bf16* __restrict__ BlT,
                                              bf16* __restrict__ uniwT, bf16* __restrict__ ffw1T,
                                              bf16* __restrict__ ffw2T) {
    int blk = blockIdx.x;               // 512 blocks
    int b = blk >> 7, t0 = (blk & 127) << 3;
    int row = threadIdx.x >> 5, o = threadIdx.x & 31;
    int tt = t0 + row;
    const float* xr = x + (size_t)(b * T + tt) * KDIM;
    const float* wr = sqw + o * KDIM;
    float acc = 0.f;
    #pragma unroll
    for (int i = 0; i < KDIM; ++i) acc += xr[i] * wr[i];
    const float inv = 0.9999950000374997f; // 1/sqrt(1+1e-5)
    x3[(size_t)(b * T + tt) * R + o] = bng[o] * acc * inv + bnb[o];

    int gid = blk * 256 + threadIdx.x;
    // conv weights, s-major K (read-coalesced)
    #pragma unroll
    for (int rep = 0; rep < 3; ++rep) {
        int e = gid + rep * 131072;
        if (e < 163840) {
            int oo = e / 320, rem = e - oo * 320;
            int i = rem / 5, s = rem - i * 5;
            BqT[oo * 320 + s * 64 + i] = f2b(wq[e]);
        } else if (e < 327680) {
            int e2 = e - 163840;
            int oo = e2 / 320, rem = e2 - oo * 320;
            int i = rem / 5, s = rem - i * 5;
            BkT[oo * 320 + s * 64 + i] = f2b(wk[e2]);
        } else if (e < 360448) {
            int e3 = e - 327680;
            BvT[e3] = f2b(wv[e3]);
        } else {
            int e4 = e - 360448;
            BlT[e4] = f2b(wl[e4]);
        }
    }
    // epilogue weights (read-coalesced): uniwT[c][d], ffw1T[j][i], ffw2T[c][j]
    {
        int e = gid;
        if (e < 65536) {
            int d = e >> 6, c = e & 63;
            uniwT[c * 1024 + d] = f2b(uniw[e]);
        } else if (e < 81920) {
            int e2 = e - 65536;
            int i = e2 >> 8, j = e2 & 255;
            ffw1T[j * 64 + i] = f2b(ffw1[e2]);
        } else if (e < 98304) {
            int e3 = e - 81920;
            int j = e3 >> 6, c = e3 & 63;
            ffw2T[c * 256 + j] = f2b(ffw2[e3]);
        }
    }
}

// ---------------- Kernel 1b: depthwise diff + excite conv + gate + pos ----------------
__global__ __launch_bounds__(256) void k1b_xin(const float* __restrict__ x3, const float* __restrict__ dww,
                                               const float* __restrict__ exw, const float* __restrict__ x,
                                               const float* __restrict__ pos, float* __restrict__ xin) {
    __shared__ float sx3[10 * R];
    __shared__ float sxp[8 * R];
    int blk = blockIdx.x;               // 512 blocks
    int b = blk >> 7, t0 = (blk & 127) << 3;
    int tid = threadIdx.x;
    for (int e = tid; e < 320; e += 256) {
        int rr = e >> 5, o = e & 31;
        int tt = t0 + rr;
        sx3[e] = (tt < T) ? x3[(size_t)(b * T + tt) * R + o] : 0.f;
    }
    __syncthreads();
    {
        int rr = tid >> 5, o = tid & 31;
        int tt = t0 + rr;
        float v;
        if (tt == T - 1) {
            v = sx3[rr * R + o];
        } else {
            float w0 = dww[o * 3 + 0], w1 = dww[o * 3 + 1], w2 = dww[o * 3 + 2];
            v = sx3[rr * R + o] * (w0 - 1.f) + sx3[(rr + 1) * R + o] * w1 + sx3[(rr + 2) * R + o] * w2;
        }
        sxp[rr * R + o] = v;
    }
    __syncthreads();
    int rr = tid >> 5, c0 = tid & 31;
    int tt = t0 + rr;
    #pragma unroll
    for (int u = 0; u < 2; ++u) {
        int c = c0 + u * 32;
        const float* ew = exw + c * R;
        float g = 0.f;
        #pragma unroll
        for (int o = 0; o < R; ++o) g += ew[o] * sxp[rr * R + o];
        float sg = sigmoidf_(g);
        size_t idx = (size_t)(b * T + tt) * KDIM + c;
        xin[idx] = x[idx] * sg + pos[tt * KDIM + c];
    }
}

// ---------------- Kernel 2 (MFMA): q/k/v/l convs + silu + head-scramble store ----------------
__global__ __launch_bounds__(256) void k2_mfma(const float* __restrict__ xin,
        const bf16* __restrict__ BqT, const bf16* __restrict__ BkT,
        const bf16* __restrict__ BvT, const bf16* __restrict__ BlT,
        const float* __restrict__ bq, const float* __restrict__ bk,
        bf16* __restrict__ qo, bf16* __restrict__ ko, bf16* __restrict__ vt, bf16* __restrict__ lo) {
    __shared__ __align__(16) bf16 sX[24][72];
    int blk = blockIdx.x;               // 512 blocks
    int sel = blk >> 8;                 // 0: q+v, 1: k+l
    int b = (blk >> 6) & 3, t0 = (blk & 63) << 4;
    int tid = threadIdx.x, w = tid >> 6, lane = tid & 63;
    int lm = lane & 15, quad = lane >> 4;

    for (int e = tid; e < 1536; e += 256) {
        int rr = e >> 6, ch = e & 63;
        int t = t0 - 8 + rr;
        sX[rr][ch] = f2b((t >= 0) ? xin[((size_t)(b * T) + t) * KDIM + ch] : 0.f);
    }
    __syncthreads();

    bf16x8s aX[10];
    #pragma unroll
    for (int ks = 0; ks < 10; ++ks)
        aX[ks] = *(const bf16x8s*)&sX[lm + 2 * (ks >> 1)][(ks & 1) * 32 + quad * 8];

    const bf16* Bd = sel ? BkT : BqT;
    const float* bias = sel ? bk : bq;
    const bf16* Bp = sel ? BlT : BvT;
    bf16* OutD = sel ? ko : qo;
    const float isg = 0.35355339059327373f; // 1/64^0.25

    for (int nt8 = 0; nt8 < 8; ++nt8) {
        int nt = w * 8 + nt8;
        int o = nt * 16 + lm;
        f32x4 acc = {0.f, 0.f, 0.f, 0.f};
        const bf16* br = Bd + (size_t)o * 320;
        #pragma unroll
        for (int ks = 0; ks < 10; ++ks) {
            bf16x8s bB = *(const bf16x8s*)&br[ks * 32 + quad * 8];
            acc = __builtin_amdgcn_mfma_f32_16x16x32_bf16(aX[ks], bB, acc, 0, 0, 0);
        }
        float bb = bias[o];
        int c = o >> 3, h = o & 7;
        #pragma unroll
        for (int r4 = 0; r4 < 4; ++r4) {
            int tt = t0 + quad * 4 + r4;
            int n = (b << 3) + (tt >> 7);
            int pp = ((tt & 127) << 3) | h;
            OutD[((size_t)n * T + pp) * KDIM + c] = f2b(siluf_(acc[r4] + bb) * isg);
        }
    }
    for (int nt8 = 0; nt8 < 8; ++nt8) {
        int nt = w * 8 + nt8;
        int o = nt * 16 + lm;
        f32x4 acc = {0.f, 0.f, 0.f, 0.f};
        const bf16* br = Bp + (size_t)o * 64;
        #pragma unroll
        for (int ks = 0; ks < 2; ++ks) {
            bf16x8s bB = *(const bf16x8s*)&br[ks * 32 + quad * 8];
            acc = __builtin_amdgcn_mfma_f32_16x16x32_bf16(aX[8 + ks], bB, acc, 0, 0, 0);
        }
        int c = o >> 3, h = o & 7;
        #pragma unroll
        for (int r4 = 0; r4 < 4; ++r4) {
            int tt = t0 + quad * 4 + r4;
            int n = (b << 3) + (tt >> 7);
            int pp = ((tt & 127) << 3) | h;
            float val = siluf_(acc[r4]);
            if (sel == 0)
                vt[((size_t)n * 64 + c) * T + pp] = f2b(val);
            else
                lo[((size_t)n * T + pp) * KDIM + c] = f2b(val);
        }
    }
}

// ---------------- Kernel 3 (tiled): local windowed causal attention (window 5) ----------------
// Block = (n, 64-row tile); stage rows t0-5..t0+63 once in LDS; 2 phases, 1 barrier.
__global__ __launch_bounds__(256) void k3_local(const bf16* __restrict__ lws, bf16* __restrict__ ol) {
    __shared__ __align__(16) bf16 sL[69][72];
    __shared__ float sP[64][6];
    int blk = blockIdx.x;               // 512 blocks: n = blk>>4, tile = blk&15
    int n = blk >> 4, t0 = (blk & 15) << 6;
    int tid = threadIdx.x;
    const bf16* base = lws + (size_t)n * T * KDIM;

    // stage: 69 rows x 8 vec8 segs = 552 slots
    for (int e = tid; e < 552; e += 256) {
        int rr = e >> 3, seg = e & 7;
        int p = t0 - 5 + rr;
        if (p >= 0) {
            *(uint4*)&sL[rr][seg * 8] = *(const uint4*)(base + (size_t)p * KDIM + seg * 8);
        } else {
            *(uint4*)&sL[rr][seg * 8] = make_uint4(0, 0, 0, 0);
        }
    }
    __syncthreads();

    int r = tid >> 2, q4 = tid & 3;     // row r (0..63), quarter-channel q4
    // phase 1: 6 window dots, 16 channels per thread, 4-lane reduce
    float acc[6];
    #pragma unroll
    for (int u = 0; u < 6; ++u) acc[u] = 0.f;
    #pragma unroll
    for (int i = 0; i < 16; ++i) {
        int ch = q4 * 16 + i;
        float lp = b2f(sL[r + 5][ch]);
        #pragma unroll
        for (int u = 0; u < 6; ++u) acc[u] += b2f(sL[r + u][ch]) * lp;
    }
    #pragma unroll
    for (int u = 0; u < 6; ++u) {
        float v = acc[u];
        v += __shfl_xor(v, 1); v += __shfl_xor(v, 2);
        acc[u] = v;
    }
    if (q4 == 0) {
        float s[6], mx;
        #pragma unroll
        for (int u = 0; u < 6; ++u) {
            int pj = t0 + r - 5 + u;
            s[u] = (pj < 0) ? NEGBIG : acc[u] * 0.125f;
        }
        mx = s[5];
        #pragma unroll
        for (int u = 0; u < 5; ++u) mx = fmaxf(mx, s[u]);
        float P[6], Z = 0.f;
        #pragma unroll
        for (int u = 0; u < 6; ++u) { P[u] = (s[u] <= NEGBIG) ? 0.f : __expf(s[u] - mx); Z += P[u]; }
        float iZ = 1.f / Z;
        #pragma unroll
        for (int u = 0; u < 6; ++u) sP[r][u] = P[u] * iZ;
    }
    __syncthreads();

    // phase 2: weighted sum, 16 channels per thread, vec8 stores
    float Pw[6];
    #pragma unroll
    for (int u = 0; u < 6; ++u) Pw[u] = sP[r][u];
    bf8u o0, o1;
    #pragma unroll
    for (int i = 0; i < 8; ++i) {
        int ch = q4 * 16 + i;
        float a0 = 0.f, a1 = 0.f;
        #pragma unroll
        for (int u = 0; u < 6; ++u) {
            a0 += Pw[u] * b2f(sL[r + u][ch]);
            a1 += Pw[u] * b2f(sL[r + u][ch + 8]);
        }
        o0.a[i] = f2b(a0);
        o1.a[i] = f2b(a1);
    }
    bf16* ob = ol + ((size_t)n * T + t0 + r) * KDIM + q4 * 16;
    *(bf16x8s*)ob = o0.v;
    *(bf16x8s*)(ob + 8) = o1.v;
}

// ---------------- Kernel 4 (MFMA, cooperative, double-buffered K/V): causal flash attention ----------------
__global__ __launch_bounds__(256) void k4_mfma(const bf16* __restrict__ qws, const bf16* __restrict__ kws,
                                               const bf16* __restrict__ vt, bf16* __restrict__ og) {
    __shared__ __align__(16) bf16 sQ[64][72];
    __shared__ __align__(16) bf16 sK[2][64][72];
    __shared__ __align__(16) bf16 sVt[2][64][72];
    __shared__ __align__(16) bf16 sPt[4][16][76];

    int i = blockIdx.x;                  // 512 blocks
    int half = i >> 8, rem = i & 255;
    int n = rem >> 3, sub = rem & 7;
    int qt = half ? (15 - sub) : sub;
    int p0 = qt << 6;
    int tid = threadIdx.x, w = tid >> 6, lane = tid & 63;
    int lm = lane & 15, quad = lane >> 4;
    int vc = tid >> 2, vj8 = tid & 3;    // V staging coords

    {
        const uint4* qg = (const uint4*)(qws + ((size_t)n * T + p0) * KDIM);
        #pragma unroll
        for (int r = 0; r < 2; ++r) { int e = tid + 256 * r; *(uint4*)&sQ[e >> 3][(e & 7) * 8] = qg[e]; }
        const uint4* kg = (const uint4*)(kws + (size_t)n * T * KDIM);
        #pragma unroll
        for (int r = 0; r < 2; ++r) { int e = tid + 256 * r; *(uint4*)&sK[0][e >> 3][(e & 7) * 8] = kg[e]; }
        const bf16* vrow = vt + ((size_t)n * 64 + vc) * T + vj8 * 16;
        *(uint4*)&sVt[0][vc][vj8 * 16]     = *(const uint4*)vrow;
        *(uint4*)&sVt[0][vc][vj8 * 16 + 8] = *(const uint4*)(vrow + 8);
    }
    __syncthreads();

    bf16x8s aQ[2];
    #pragma unroll
    for (int ks = 0; ks < 2; ++ks) aQ[ks] = *(const bf16x8s*)&sQ[w * 16 + lm][ks * 32 + quad * 8];

    f32x4 O[4];
    float m_i[4], l_i[4];
    #pragma unroll
    for (int t = 0; t < 4; ++t) { O[t][0] = 0.f; O[t][1] = 0.f; O[t][2] = 0.f; O[t][3] = 0.f; }
    #pragma unroll
    for (int r4 = 0; r4 < 4; ++r4) { m_i[r4] = NEGBIG; l_i[r4] = 0.f; }

    int prow_base = p0 + w * 16 + quad * 4;
    for (int jt = 0; jt <= qt; ++jt) {
        int j0 = jt << 6;
        int cur = jt & 1, nxt = cur ^ 1;
        bool pref = (jt < qt);
        uint4 pk0, pk1, pv0, pv1;
        if (pref) {
            int j0n = j0 + 64;
            const uint4* kg = (const uint4*)(kws + ((size_t)n * T + j0n) * KDIM);
            pk0 = kg[tid]; pk1 = kg[tid + 256];
            const bf16* vrow = vt + ((size_t)n * 64 + vc) * T + j0n + vj8 * 16;
            pv0 = *(const uint4*)vrow;
            pv1 = *(const uint4*)(vrow + 8);
        }
        f32x4 S[4];
        #pragma unroll
        for (int nt = 0; nt < 4; ++nt) {
            f32x4 acc = {0.f, 0.f, 0.f, 0.f};
            #pragma unroll
            for (int ks = 0; ks < 2; ++ks) {
                bf16x8s bK = *(const bf16x8s*)&sK[cur][nt * 16 + lm][ks * 32 + quad * 8];
                acc = __builtin_amdgcn_mfma_f32_16x16x32_bf16(aQ[ks], bK, acc, 0, 0, 0);
            }
            S[nt] = acc;
        }
        float mt[4];
        #pragma unroll
        for (int r4 = 0; r4 < 4; ++r4) mt[r4] = NEGBIG;
        #pragma unroll
        for (int nt = 0; nt < 4; ++nt) {
            int jcol = j0 + nt * 16 + lm;
            #pragma unroll
            for (int r4 = 0; r4 < 4; ++r4) {
                float s = (jcol <= prow_base + r4) ? S[nt][r4] : NEGBIG;
                S[nt][r4] = s;
                mt[r4] = fmaxf(mt[r4], s);
            }
        }
        #pragma unroll
        for (int r4 = 0; r4 < 4; ++r4) {
            float v = mt[r4];
            v = fmaxf(v, __shfl_xor(v, 1)); v = fmaxf(v, __shfl_xor(v, 2));
            v = fmaxf(v, __shfl_xor(v, 4)); v = fmaxf(v, __shfl_xor(v, 8));
            mt[r4] = v;
        }
        float alpha[4], ps[4];
        #pragma unroll
        for (int r4 = 0; r4 < 4; ++r4) {
            float mnew = fmaxf(m_i[r4], mt[r4]);
            alpha[r4] = __expf(m_i[r4] - mnew);
            m_i[r4] = mnew; ps[r4] = 0.f;
        }
        #pragma unroll
        for (int nt = 0; nt < 4; ++nt) {
            #pragma unroll
            for (int r4 = 0; r4 < 4; ++r4) {
                float p = (S[nt][r4] <= NEGBIG) ? 0.f : __expf(S[nt][r4] - m_i[r4]);
                ps[r4] += p;
                sPt[w][quad * 4 + r4][nt * 16 + lm] = f2b(p);
            }
        }
        #pragma unroll
        for (int r4 = 0; r4 < 4; ++r4) {
            float v = ps[r4];
            v += __shfl_xor(v, 1); v += __shfl_xor(v, 2);
            v += __shfl_xor(v, 4); v += __shfl_xor(v, 8);
            l_i[r4] = l_i[r4] * alpha[r4] + v;
        }
        #pragma unroll
        for (int t = 0; t < 4; ++t)
            #pragma unroll
            for (int r4 = 0; r4 < 4; ++r4) O[t][r4] *= alpha[r4];
        __builtin_amdgcn_wave_barrier();
        int ksmax = (jt == qt) ? (w >> 1) : 1;
        for (int ks = 0; ks <= ksmax; ++ks) {
            bf16x4s plo = *(const bf16x4s*)&sPt[w][lm][ks * 32 + quad * 8];
            bf16x4s phi = *(const bf16x4s*)&sPt[w][lm][ks * 32 + quad * 8 + 4];
            bf16x8s aP;
            #pragma unroll
            for (int ii = 0; ii < 4; ++ii) { aP[ii] = plo[ii]; aP[ii + 4] = phi[ii]; }
            #pragma unroll
            for (int ct = 0; ct < 4; ++ct) {
                bf16x8s bV = *(const bf16x8s*)&sVt[cur][ct * 16 + lm][ks * 32 + quad * 8];
                O[ct] = __builtin_amdgcn_mfma_f32_16x16x32_bf16(aP, bV, O[ct], 0, 0, 0);
            }
        }
        if (pref) {
            int e0 = tid, e1 = tid + 256;
            *(uint4*)&sK[nxt][e0 >> 3][(e0 & 7) * 8] = pk0;
            *(uint4*)&sK[nxt][e1 >> 3][(e1 & 7) * 8] = pk1;
            *(uint4*)&sVt[nxt][vc][vj8 * 16]     = pv0;
            *(uint4*)&sVt[nxt][vc][vj8 * 16 + 8] = pv1;
        }
        __syncthreads();
    }
    #pragma unroll
    for (int r4 = 0; r4 < 4; ++r4) {
        int p = p0 + w * 16 + quad * 4 + r4;
        float inv = 1.f / l_i[r4];
        bf16* ob = og + ((size_t)n * T + p) * KDIM;
        #pragma unroll
        for (int t = 0; t < 4; ++t) ob[t * 16 + lm] = f2b(O[t][r4] * inv);
    }
}

// ---------------- Kernel 5 (MFMA): gate/concat + uni GEMM + LN1 + FF + LN2 ----------------
__global__ __launch_bounds__(256) void k5_mfma(const bf16* __restrict__ og, const bf16* __restrict__ olw,
        const bf16* __restrict__ uniwT, const float* __restrict__ unib, const float* __restrict__ xin,
        const float* __restrict__ ln1g, const float* __restrict__ ln1b,
        const bf16* __restrict__ ffw1T, const float* __restrict__ ffb1,
        const bf16* __restrict__ ffw2T, const float* __restrict__ ffb2,
        const float* __restrict__ ln2g, const float* __restrict__ ln2b,
        float* __restrict__ out) {
    __shared__ __align__(16) bf16 sU[16][1032];
    __shared__ float sY[16][68];
    __shared__ __align__(16) bf16 sYb[16][72];
    __shared__ __align__(16) bf16 sH[16][264];
    int blk = blockIdx.x;               // 256 blocks
    int b = blk >> 6, t0 = (blk & 63) << 4;
    int tid = threadIdx.x, w = tid >> 6, lane = tid & 63;
    int lm = lane & 15, quad = lane >> 4;

    #pragma unroll
    for (int it = 0; it < 8; ++it) {
        int e = tid + it * 256;
        int r = e >> 7, dd = e & 127;
        int hh = dd >> 3, cs = dd & 7;
        int hi = hh & 7;
        size_t rowoff = ((size_t)((b * NH + hi) * T) + t0 + r) * KDIM + cs * 8;
        bf8u gv; gv.v = *(const bf16x8s*)(og + rowoff);
        bf8u res;
        if (hh < 8) {
            bf8u lv; lv.v = *(const bf16x8s*)(olw + rowoff);
            #pragma unroll
            for (int k = 0; k < 8; ++k) {
                float g = b2f(gv.a[k]);
                res.a[k] = f2b((1.f - sigmoidf_(g)) * b2f(lv.a[k]));
            }
        } else {
            #pragma unroll
            for (int k = 0; k < 8; ++k) {
                float g = b2f(gv.a[k]);
                res.a[k] = f2b(sigmoidf_(g) * g);
            }
        }
        *(bf16x8s*)&sU[r][hh * 64 + cs * 8] = res.v;
    }
    __syncthreads();

    int col = w * 16 + lm;
    f32x4 accU = {0.f, 0.f, 0.f, 0.f};
    const bf16* ur = uniwT + (size_t)col * 1024;
    #pragma unroll
    for (int ks = 0; ks < 32; ++ks) {
        bf16x8s aU = *(const bf16x8s*)&sU[lm][ks * 32 + quad * 8];
        bf16x8s bU = *(const bf16x8s*)&ur[ks * 32 + quad * 8];
        accU = __builtin_amdgcn_mfma_f32_16x16x32_bf16(aU, bU, accU, 0, 0, 0);
    }
    float ub = unib[col];
    #pragma unroll
    for (int r4 = 0; r4 < 4; ++r4) {
        int row = quad * 4 + r4;
        float a = siluf_(accU[r4] + ub);
        sY[row][col] = a + xin[((size_t)(b * T) + t0 + row) * KDIM + col];
    }
    __syncthreads();

    #pragma unroll
    for (int i = 0; i < 4; ++i) {
        int row = w + 4 * i;
        float yv = sY[row][lane];
        float mean = waveSum64(yv) * (1.f / 64.f);
        float dv = yv - mean;
        float var = waveSum64(dv * dv) * (1.f / 64.f);
        float y = dv * rsqrtf(var + 1e-5f) * ln1g[lane] + ln1b[lane];
        sY[row][lane] = y;
        sYb[row][lane] = f2b(y);
    }
    __syncthreads();

    bf16x8s aY[2];
    #pragma unroll
    for (int ks = 0; ks < 2; ++ks) aY[ks] = *(const bf16x8s*)&sYb[lm][ks * 32 + quad * 8];
    #pragma unroll
    for (int u = 0; u < 4; ++u) {
        int j = (w * 4 + u) * 16 + lm;
        f32x4 acc = {0.f, 0.f, 0.f, 0.f};
        const bf16* fr = ffw1T + (size_t)j * 64;
        #pragma unroll
        for (int ks = 0; ks < 2; ++ks) {
            bf16x8s bF = *(const bf16x8s*)&fr[ks * 32 + quad * 8];
            acc = __builtin_amdgcn_mfma_f32_16x16x32_bf16(aY[ks], bF, acc, 0, 0, 0);
        }
        float b1 = ffb1[j];
        #pragma unroll
        for (int r4 = 0; r4 < 4; ++r4)
            sH[quad * 4 + r4][j] = f2b(fmaxf(acc[r4] + b1, 0.f));
    }
    __syncthreads();

    f32x4 accF = {0.f, 0.f, 0.f, 0.f};
    const bf16* f2r = ffw2T + (size_t)col * 256;
    #pragma unroll
    for (int ks = 0; ks < 8; ++ks) {
        bf16x8s aH = *(const bf16x8s*)&sH[lm][ks * 32 + quad * 8];
        bf16x8s bF2 = *(const bf16x8s*)&f2r[ks * 32 + quad * 8];
        accF = __builtin_amdgcn_mfma_f32_16x16x32_bf16(aH, bF2, accF, 0, 0, 0);
    }
    float b2 = ffb2[col];
    #pragma unroll
    for (int r4 = 0; r4 < 4; ++r4) {
        int row = quad * 4 + r4;
        sY[row][col] = (accF[r4] + b2) + sY[row][col];
    }
    __syncthreads();

    #pragma unroll
    for (int i = 0; i < 4; ++i) {
        int row = w + 4 * i;
        float z = sY[row][lane];
        float mean = waveSum64(z) * (1.f / 64.f);
        float dv = z - mean;
        float var = waveSum64(dv * dv) * (1.f / 64.f);
        out[((size_t)(b * T) + t0 + row) * KDIM + lane] =
            dv * rsqrtf(var + 1e-5f) * ln2g[lane] + ln2b[lane];
    }
}

extern "C" void kernel_launch(void* const* d_in, const int* in_sizes, int n_in,
                              void* d_out, int out_size, void* d_ws, size_t ws_size,
                              hipStream_t stream) {
    (void)in_sizes; (void)n_in; (void)out_size; (void)ws_size;
    const float* x    = (const float*)d_in[0];
    const float* sqw  = (const float*)d_in[1];
    const float* bng  = (const float*)d_in[2];
    const float* bnb  = (const float*)d_in[3];
    const float* dww  = (const float*)d_in[4];
    const float* exw  = (const float*)d_in[5];
    const float* pos  = (const float*)d_in[6];
    const float* wq   = (const float*)d_in[7];
    const float* bq   = (const float*)d_in[8];
    const float* wk   = (const float*)d_in[9];
    const float* bk   = (const float*)d_in[10];
    const float* wv   = (const float*)d_in[11];
    const float* wl   = (const float*)d_in[12];
    const float* uniw = (const float*)d_in[13];
    const float* unib = (const float*)d_in[14];
    const float* ln1g = (const float*)d_in[15];
    const float* ln1b = (const float*)d_in[16];
    const float* ln2g = (const float*)d_in[17];
    const float* ln2b = (const float*)d_in[18];
    const float* ffw1 = (const float*)d_in[19];
    const float* ffb1 = (const float*)d_in[20];
    const float* ffw2 = (const float*)d_in[21];
    const float* ffb2 = (const float*)d_in[22];

    // ws layout — ~22.5 MiB.
    char* ws = (char*)d_ws;
    float* xin   = (float*)(ws);                  // fp32 1.0 MiB
    bf16*  qog   = (bf16*)(ws + 0x100000);        // 4 MiB  q, then og in-place
    bf16*  kw_   = (bf16*)(ws + 0x500000);        // 4 MiB
    bf16*  vtw   = (bf16*)(ws + 0x900000);        // 4 MiB  (transposed v)
    bf16*  lw_   = (bf16*)(ws + 0xD00000);        // 4 MiB
    bf16*  olw   = (bf16*)(ws + 0x1100000);       // 4 MiB
    float* x3    = (float*)(ws + 0x1500000);      // fp32 0.5 MiB
    bf16*  BqT   = (bf16*)(ws + 0x1580000);       // 320 KiB
    bf16*  BkT   = (bf16*)(ws + 0x15D0000);       // 320 KiB
    bf16*  BvT   = (bf16*)(ws + 0x1620000);       // 64 KiB
    bf16*  BlT   = (bf16*)(ws + 0x1630000);       // 64 KiB
    bf16*  uniwT = (bf16*)(ws + 0x1640000);       // 128 KiB
    bf16*  ffw1T = (bf16*)(ws + 0x1660000);       // 32 KiB
    bf16*  ffw2T = (bf16*)(ws + 0x1668000);       // 32 KiB (end 0x1670000)

    k1a_x3 <<<512, 256, 0, stream>>>(x, sqw, bng, bnb, wq, wk, wv, wl, uniw, ffw1, ffw2,
                                     x3, BqT, BkT, BvT, BlT, uniwT, ffw1T, ffw2T);
    k1b_xin<<<512, 256, 0, stream>>>(x3, dww, exw, x, pos, xin);
    k2_mfma<<<512, 256, 0, stream>>>(xin, BqT, BkT, BvT, BlT, bq, bk, qog, kw_, vtw, lw_);
    k3_local<<<512, 256, 0, stream>>>(lw_, olw);
    k4_mfma<<<512, 256, 0, stream>>>(qog, kw_, vtw, qog);   // og overwrites q in-place
    k5_mfma<<<256, 256, 0, stream>>>(qog, olw, uniwT, unib, xin,
                                     ln1g, ln1b, ffw1T, ffb1, ffw2T, ffb2, ln2g, ln2b,
                                     (float*)d_out);
}